// Round 1
// baseline (8830.192 us; speedup 1.0000x reference)
//
#include <hip/hip_runtime.h>

// Problem constants (match reference)
#define U_N 100000
#define I_N 200000
#define D   64
#define NNZ_UI 2000000
#define NNZ_SOC 1000000
#define LN_EPS 1e-5f
#define LSLOPE 0.01f

// ---------------------------------------------------------------------------
// zero a float buffer (float4-vectorized)
__global__ void zero_f4(float4* __restrict__ p, int n4) {
    int i = blockIdx.x * blockDim.x + threadIdx.x;
    if (i < n4) p[i] = make_float4(0.f, 0.f, 0.f, 0.f);
}

// copy user_emb into two output slots
__global__ void copy2_f4(const float4* __restrict__ src, float4* __restrict__ d1,
                         float4* __restrict__ d2, int n4) {
    int i = blockIdx.x * blockDim.x + threadIdx.x;
    if (i < n4) {
        float4 v = src[i];
        d1[i] = v;
        d2[i] = v;
    }
}

// ---------------------------------------------------------------------------
// COO SpMM via scatter atomics: out[rows[e]] += vals[e] * x[cols[e]]
// 16 threads per edge, each handles a float4 (4 dims).
__global__ __launch_bounds__(256) void spmm_atomic(
    const int* __restrict__ rows, const int* __restrict__ cols,
    const float* __restrict__ vals, const float* __restrict__ x,
    float* __restrict__ out, int nnz)
{
    int t = blockIdx.x * blockDim.x + threadIdx.x;
    int e = t >> 4;
    if (e >= nnz) return;
    int sub = t & 15;
    int r = rows[e];
    int c = cols[e];
    float v = vals[e];
    float4 xv = *(const float4*)(x + (size_t)c * D + sub * 4);
    float* op = out + (size_t)r * D + sub * 4;
    atomicAdd(op + 0, v * xv.x);
    atomicAdd(op + 1, v * xv.y);
    atomicAdd(op + 2, v * xv.z);
    atomicAdd(op + 3, v * xv.w);
}

// ---------------------------------------------------------------------------
// Fused: h = leaky_relu(agg @ W^T + bias); y = LayerNorm(cur + h)*gamma + beta
// Block = 256 threads = 4 groups of 64 lanes; each group handles 4 rows.
// Requires n % 16 == 0 (holds: U=100000, I=200000).
__global__ __launch_bounds__(256) void xform_ln(
    const float* __restrict__ agg, const float* __restrict__ cur,
    const float* __restrict__ W,     // [64][64] row-major; out_j = sum_k agg_k * W[j][k]
    const float* __restrict__ bias,  // [64]
    const float* __restrict__ gamma, const float* __restrict__ beta,
    float* __restrict__ dst, int n)
{
    __shared__ float Wt[64][65];       // Wt[k][j] = W[j*64+k]  (conflict-free reads)
    __shared__ float arow[4][64][4];   // [group][k][r]

    for (int i = threadIdx.x; i < 4096; i += 256)
        Wt[i & 63][i >> 6] = W[i];

    const int lane = threadIdx.x & 63;
    const int grp  = threadIdx.x >> 6;
    const int rb   = (blockIdx.x * 4 + grp) * 4;   // first of this group's 4 rows

    // stage the 4 agg rows: lane l loads row (l>>4), float4 chunk (l&15)
    {
        int r = lane >> 4, c = lane & 15;
        float4 v = *(const float4*)(agg + (size_t)(rb + r) * D + c * 4);
        arow[grp][c * 4 + 0][r] = v.x;
        arow[grp][c * 4 + 1][r] = v.y;
        arow[grp][c * 4 + 2][r] = v.z;
        arow[grp][c * 4 + 3][r] = v.w;
    }
    __syncthreads();

    float h0 = 0.f, h1 = 0.f, h2 = 0.f, h3 = 0.f;
    #pragma unroll
    for (int k = 0; k < 64; ++k) {
        float w  = Wt[k][lane];
        float4 a = *(const float4*)&arow[grp][k][0];  // broadcast
        h0 += w * a.x; h1 += w * a.y; h2 += w * a.z; h3 += w * a.w;
    }

    const float bj  = bias[lane];
    const float gj  = gamma[lane];
    const float bej = beta[lane];

    float hr[4] = {h0, h1, h2, h3};
    #pragma unroll
    for (int r = 0; r < 4; ++r) {
        float h = hr[r] + bj;
        h = h > 0.f ? h : LSLOPE * h;
        float x = cur[(size_t)(rb + r) * D + lane] + h;
        float s = x, s2 = x * x;
        #pragma unroll
        for (int m = 32; m >= 1; m >>= 1) {
            s  += __shfl_xor(s, m, 64);
            s2 += __shfl_xor(s2, m, 64);
        }
        float mean = s * (1.f / 64.f);
        float var  = s2 * (1.f / 64.f) - mean * mean;
        float y = (x - mean) * rsqrtf(var + LN_EPS) * gj + bej;
        dst[(size_t)(rb + r) * D + lane] = y;
    }
}

// ---------------------------------------------------------------------------
extern "C" void kernel_launch(void* const* d_in, const int* in_sizes, int n_in,
                              void* d_out, int out_size, void* d_ws, size_t ws_size,
                              hipStream_t stream)
{
    const float* user_emb = (const float*)d_in[0];
    const float* item_emb = (const float*)d_in[1];
    const int*   ui_rows  = (const int*)d_in[2];
    const int*   ui_cols  = (const int*)d_in[3];
    const float* ui_vals  = (const float*)d_in[4];
    const int*   soc_rows = (const int*)d_in[5];
    const int*   soc_cols = (const int*)d_in[6];
    const float* soc_vals = (const float*)d_in[7];
    const float* ui_W     = (const float*)d_in[8];   // [2][64][64]
    const float* ui_b     = (const float*)d_in[9];   // [2][64]
    const float* soc_W    = (const float*)d_in[10];
    const float* soc_b    = (const float*)d_in[11];
    const float* ln_ui_g  = (const float*)d_in[12];
    const float* ln_ui_b  = (const float*)d_in[13];
    const float* ln_soc_g = (const float*)d_in[14];
    const float* ln_soc_b = (const float*)d_in[15];

    float* out = (float*)d_out;
    const size_t UD = (size_t)U_N * D;   // 6.4M
    const size_t ID = (size_t)I_N * D;   // 12.8M

    // output slots
    float* o_ui0 = out;            // user_emb
    float* o_ui1 = out + UD;       // cu after layer 0
    float* o_ui2 = out + 2 * UD;   // cu after layer 1
    float* o_s0  = out + 3 * UD;   // user_emb
    float* o_s1  = out + 4 * UD;   // cs after layer 0
    float* o_s2  = out + 5 * UD;   // cs after layer 1
    float* o_ci  = out + 6 * UD;   // final ci (also holds ci intermediate)

    // workspace: ua [U*D] then ia [I*D]
    float* ua = (float*)d_ws;
    float* ia = ua + UD;

    const int nthr = 256;
    const int spmm_blk_ui  = (NNZ_UI  * 16 + nthr - 1) / nthr;
    const int spmm_blk_soc = (NNZ_SOC * 16 + nthr - 1) / nthr;
    const int zero_both = (int)((UD + ID) / 4 + nthr - 1) / nthr;
    const int zero_ua   = (int)(UD / 4 + nthr - 1) / nthr;
    const int cp_blk    = (int)(UD / 4 + nthr - 1) / nthr;
    const int xl_u = U_N / 16;
    const int xl_i = I_N / 16;

    // ui_embs[0] = soc_embs[0] = user_emb
    copy2_f4<<<cp_blk, nthr, 0, stream>>>((const float4*)user_emb,
                                          (float4*)o_ui0, (float4*)o_s0, (int)(UD / 4));

    // ---------------- UI layer 0 ----------------
    zero_f4<<<zero_both, nthr, 0, stream>>>((float4*)ua, (int)((UD + ID) / 4));
    spmm_atomic<<<spmm_blk_ui, nthr, 0, stream>>>(ui_rows, ui_cols, ui_vals, item_emb, ua, NNZ_UI);
    spmm_atomic<<<spmm_blk_ui, nthr, 0, stream>>>(ui_cols, ui_rows, ui_vals, user_emb, ia, NNZ_UI);
    xform_ln<<<xl_u, nthr, 0, stream>>>(ua, user_emb, ui_W, ui_b, ln_ui_g, ln_ui_b, o_ui1, U_N);
    xform_ln<<<xl_i, nthr, 0, stream>>>(ia, item_emb, ui_W, ui_b, ln_ui_g, ln_ui_b, o_ci, I_N);

    // ---------------- UI layer 1 ----------------
    zero_f4<<<zero_both, nthr, 0, stream>>>((float4*)ua, (int)((UD + ID) / 4));
    spmm_atomic<<<spmm_blk_ui, nthr, 0, stream>>>(ui_rows, ui_cols, ui_vals, o_ci, ua, NNZ_UI);
    spmm_atomic<<<spmm_blk_ui, nthr, 0, stream>>>(ui_cols, ui_rows, ui_vals, o_ui1, ia, NNZ_UI);
    xform_ln<<<xl_u, nthr, 0, stream>>>(ua, o_ui1, ui_W + 4096, ui_b + 64,
                                        ln_ui_g + 64, ln_ui_b + 64, o_ui2, U_N);
    xform_ln<<<xl_i, nthr, 0, stream>>>(ia, o_ci, ui_W + 4096, ui_b + 64,
                                        ln_ui_g + 64, ln_ui_b + 64, o_ci, I_N);

    // ---------------- Social layer 0 ----------------
    zero_f4<<<zero_ua, nthr, 0, stream>>>((float4*)ua, (int)(UD / 4));
    spmm_atomic<<<spmm_blk_soc, nthr, 0, stream>>>(soc_rows, soc_cols, soc_vals, user_emb, ua, NNZ_SOC);
    xform_ln<<<xl_u, nthr, 0, stream>>>(ua, user_emb, soc_W, soc_b, ln_soc_g, ln_soc_b, o_s1, U_N);

    // ---------------- Social layer 1 ----------------
    zero_f4<<<zero_ua, nthr, 0, stream>>>((float4*)ua, (int)(UD / 4));
    spmm_atomic<<<spmm_blk_soc, nthr, 0, stream>>>(soc_rows, soc_cols, soc_vals, o_s1, ua, NNZ_SOC);
    xform_ln<<<xl_u, nthr, 0, stream>>>(ua, o_s1, soc_W + 4096, soc_b + 64,
                                        ln_soc_g + 64, ln_soc_b + 64, o_s2, U_N);
}

// Round 2
// 1272.136 us; speedup vs baseline: 6.9412x; 6.9412x over previous
//
#include <hip/hip_runtime.h>

// Problem constants (match reference)
#define U_N 100000
#define I_N 200000
#define D   64
#define NNZ_UI 2000000
#define NNZ_SOC 1000000
#define LN_EPS 1e-5f
#define LSLOPE 0.01f
#define SCAN_CHUNK 1024   // elements per block in the scan (256 thr x 4)

// ---------------------------------------------------------------------------
__global__ void zero_i4(int4* __restrict__ p, int n4) {
    int i = blockIdx.x * blockDim.x + threadIdx.x;
    if (i < n4) p[i] = make_int4(0, 0, 0, 0);
}

// copy user_emb into two output slots
__global__ void copy2_f4(const float4* __restrict__ src, float4* __restrict__ d1,
                         float4* __restrict__ d2, int n4) {
    int i = blockIdx.x * blockDim.x + threadIdx.x;
    if (i < n4) {
        float4 v = src[i];
        d1[i] = v;
        d2[i] = v;
    }
}

// ---------------------------------------------------------------------------
// CSR build: histogram -> exclusive scan -> scatter (rptr ends up "shifted":
// after scatter, rptr[r] == end of row r; start of row r is rptr[r-1] (0 for r=0)).

__global__ void hist_k(const int* __restrict__ rows, int* __restrict__ cnt, int nnz) {
    int i = blockIdx.x * blockDim.x + threadIdx.x;
    if (i < nnz) atomicAdd(&cnt[rows[i]], 1);
}

// pass 1: per-block sums of SCAN_CHUNK elements
__global__ __launch_bounds__(256) void scan_pass1(const int* __restrict__ cnt, int n,
                                                  int* __restrict__ bsum) {
    int base = blockIdx.x * SCAN_CHUNK + threadIdx.x * 4;
    int s = 0;
    #pragma unroll
    for (int q = 0; q < 4; ++q) {
        int idx = base + q;
        if (idx < n) s += cnt[idx];
    }
    #pragma unroll
    for (int m = 1; m < 64; m <<= 1) s += __shfl_xor(s, m, 64);
    __shared__ int ws[4];
    if ((threadIdx.x & 63) == 0) ws[threadIdx.x >> 6] = s;
    __syncthreads();
    if (threadIdx.x == 0) bsum[blockIdx.x] = ws[0] + ws[1] + ws[2] + ws[3];
}

// pass 2: single-block exclusive scan of bsum[nb], nb <= 256
__global__ __launch_bounds__(256) void scan_pass2(int* __restrict__ bsum, int nb) {
    int t = threadIdx.x;
    int v = (t < nb) ? bsum[t] : 0;
    int lane = t & 63, w = t >> 6;
    int x = v;
    #pragma unroll
    for (int m = 1; m < 64; m <<= 1) {
        int y = __shfl_up(x, m, 64);
        if (lane >= m) x += y;
    }
    __shared__ int wtot[4];
    if (lane == 63) wtot[w] = x;
    __syncthreads();
    int off = 0;
    for (int i = 0; i < w; ++i) off += wtot[i];
    int incl = x + off;
    if (t < nb) bsum[t] = incl - v;   // exclusive
}

// pass 3: local exclusive scan + block offset, in place (cnt -> row_ptr starts)
__global__ __launch_bounds__(256) void scan_pass3(int* __restrict__ cnt, int n,
                                                  const int* __restrict__ bsum) {
    int base = blockIdx.x * SCAN_CHUNK + threadIdx.x * 4;
    int v[4];
    int s = 0;
    #pragma unroll
    for (int q = 0; q < 4; ++q) {
        int idx = base + q;
        v[q] = (idx < n) ? cnt[idx] : 0;
        s += v[q];
    }
    // exclusive scan of per-thread sums across the block
    int lane = threadIdx.x & 63, w = threadIdx.x >> 6;
    int x = s;
    #pragma unroll
    for (int m = 1; m < 64; m <<= 1) {
        int y = __shfl_up(x, m, 64);
        if (lane >= m) x += y;
    }
    __shared__ int wtot[4];
    if (lane == 63) wtot[w] = x;
    __syncthreads();
    int off = 0;
    for (int i = 0; i < w; ++i) off += wtot[i];
    int run = bsum[blockIdx.x] + (x - s) + off;
    #pragma unroll
    for (int q = 0; q < 4; ++q) {
        int idx = base + q;
        int t = v[q];
        if (idx < n) cnt[idx] = run;
        run += t;
    }
}

__global__ void scatter_k(const int* __restrict__ rows, const int* __restrict__ cols,
                          const float* __restrict__ vals, int* __restrict__ rptr,
                          int2* __restrict__ pairs, int nnz) {
    int i = blockIdx.x * blockDim.x + threadIdx.x;
    if (i >= nnz) return;
    int r = rows[i];
    int pos = atomicAdd(&rptr[r], 1);
    pairs[pos] = make_int2(cols[i], __float_as_int(vals[i]));
}

// ---------------------------------------------------------------------------
// Fused: agg = CSR-gather SpMM row; h = leaky_relu(agg @ W^T + b);
//        y = LN(cur + h)*gamma + beta.
// Block = 256 threads = 4 waves; each wave handles 4 rows via 16-lane groups.
__global__ __launch_bounds__(256) void spmm_xln(
    const int* __restrict__ rptr,       // shifted: rptr[r] = end of row r
    const int2* __restrict__ pairs,     // (col, float-bits val)
    const float* __restrict__ x,        // gather source [*,64]
    const float* __restrict__ cur,      // residual input [n,64]
    const float* __restrict__ W,        // [64][64] row-major
    const float* __restrict__ bias, const float* __restrict__ gamma,
    const float* __restrict__ beta, float* __restrict__ dst, int n)
{
    __shared__ float Wt[64][65];
    __shared__ float arow[4][64][4];

    for (int i = threadIdx.x; i < 4096; i += 256)
        Wt[i & 63][i >> 6] = W[i];

    const int lane = threadIdx.x & 63;
    const int grp  = threadIdx.x >> 6;
    const int rb   = blockIdx.x * 16 + grp * 4;
    const int r    = lane >> 4;      // row within group
    const int sub  = lane & 15;      // float4 chunk within row
    const int row  = rb + r;

    float4 acc = make_float4(0.f, 0.f, 0.f, 0.f);
    if (row < n) {
        int start = (row == 0) ? 0 : rptr[row - 1];
        int end   = rptr[row];
        for (int e = start; e < end; ++e) {
            int2 p = pairs[e];
            float v = __int_as_float(p.y);
            float4 xv = *(const float4*)(x + (size_t)p.x * D + sub * 4);
            acc.x += v * xv.x; acc.y += v * xv.y;
            acc.z += v * xv.z; acc.w += v * xv.w;
        }
    }
    arow[grp][sub * 4 + 0][r] = acc.x;
    arow[grp][sub * 4 + 1][r] = acc.y;
    arow[grp][sub * 4 + 2][r] = acc.z;
    arow[grp][sub * 4 + 3][r] = acc.w;
    __syncthreads();

    float h0 = 0.f, h1 = 0.f, h2 = 0.f, h3 = 0.f;
    #pragma unroll
    for (int k = 0; k < 64; ++k) {
        float w  = Wt[k][lane];
        float4 a = *(const float4*)&arow[grp][k][0];  // broadcast
        h0 += w * a.x; h1 += w * a.y; h2 += w * a.z; h3 += w * a.w;
    }

    const float bj  = bias[lane];
    const float gj  = gamma[lane];
    const float bej = beta[lane];

    float hr[4] = {h0, h1, h2, h3};
    #pragma unroll
    for (int rr = 0; rr < 4; ++rr) {
        float h = hr[rr] + bj;
        h = h > 0.f ? h : LSLOPE * h;
        float xv = cur[(size_t)(rb + rr) * D + lane] + h;
        float s = xv, s2 = xv * xv;
        #pragma unroll
        for (int m = 32; m >= 1; m >>= 1) {
            s  += __shfl_xor(s, m, 64);
            s2 += __shfl_xor(s2, m, 64);
        }
        float mean = s * (1.f / 64.f);
        float var  = s2 * (1.f / 64.f) - mean * mean;
        float y = (xv - mean) * rsqrtf(var + LN_EPS) * gj + bej;
        dst[(size_t)(rb + rr) * D + lane] = y;
    }
}

// ---------------------------------------------------------------------------
extern "C" void kernel_launch(void* const* d_in, const int* in_sizes, int n_in,
                              void* d_out, int out_size, void* d_ws, size_t ws_size,
                              hipStream_t stream)
{
    const float* user_emb = (const float*)d_in[0];
    const float* item_emb = (const float*)d_in[1];
    const int*   ui_rows  = (const int*)d_in[2];
    const int*   ui_cols  = (const int*)d_in[3];
    const float* ui_vals  = (const float*)d_in[4];
    const int*   soc_rows = (const int*)d_in[5];
    const int*   soc_cols = (const int*)d_in[6];
    const float* soc_vals = (const float*)d_in[7];
    const float* ui_W     = (const float*)d_in[8];
    const float* ui_b     = (const float*)d_in[9];
    const float* soc_W    = (const float*)d_in[10];
    const float* soc_b    = (const float*)d_in[11];
    const float* ln_ui_g  = (const float*)d_in[12];
    const float* ln_ui_b  = (const float*)d_in[13];
    const float* ln_soc_g = (const float*)d_in[14];
    const float* ln_soc_b = (const float*)d_in[15];

    float* out = (float*)d_out;
    const size_t UD = (size_t)U_N * D;
    const size_t ID = (size_t)I_N * D;

    float* o_ui0 = out;
    float* o_ui1 = out + UD;
    float* o_ui2 = out + 2 * UD;
    float* o_s0  = out + 3 * UD;
    float* o_s1  = out + 4 * UD;
    float* o_s2  = out + 5 * UD;
    float* o_ci  = out + 6 * UD;   // item intermediate + final

    // workspace layout
    int2* pairs_ui  = (int2*)d_ws;                    // 2M
    int2* pairs_uiT = pairs_ui + NNZ_UI;              // 2M
    int2* pairs_soc = pairs_uiT + NNZ_UI;             // 1M
    int*  rp_ui     = (int*)(pairs_soc + NNZ_SOC);    // U
    int*  rp_uiT    = rp_ui + U_N;                    // I
    int*  rp_soc    = rp_uiT + I_N;                   // U
    int*  bsum      = rp_soc + U_N;                   // 256

    const int nthr = 256;
    const int nb_u = (U_N + SCAN_CHUNK - 1) / SCAN_CHUNK;   // 98
    const int nb_i = (I_N + SCAN_CHUNK - 1) / SCAN_CHUNK;   // 196

    // 1) zero the 3 count arrays (contiguous: U + I + U ints)
    {
        int ntot = U_N + I_N + U_N;   // 400000, divisible by 4
        zero_i4<<<(ntot / 4 + nthr - 1) / nthr, nthr, 0, stream>>>((int4*)rp_ui, ntot / 4);
    }

    // 2) histograms
    hist_k<<<(NNZ_UI + nthr - 1) / nthr, nthr, 0, stream>>>(ui_rows, rp_ui, NNZ_UI);
    hist_k<<<(NNZ_UI + nthr - 1) / nthr, nthr, 0, stream>>>(ui_cols, rp_uiT, NNZ_UI);
    hist_k<<<(NNZ_SOC + nthr - 1) / nthr, nthr, 0, stream>>>(soc_rows, rp_soc, NNZ_SOC);

    // 3) exclusive scans (sequential on stream; one bsum buffer)
    scan_pass1<<<nb_u, nthr, 0, stream>>>(rp_ui, U_N, bsum);
    scan_pass2<<<1, nthr, 0, stream>>>(bsum, nb_u);
    scan_pass3<<<nb_u, nthr, 0, stream>>>(rp_ui, U_N, bsum);

    scan_pass1<<<nb_i, nthr, 0, stream>>>(rp_uiT, I_N, bsum);
    scan_pass2<<<1, nthr, 0, stream>>>(bsum, nb_i);
    scan_pass3<<<nb_i, nthr, 0, stream>>>(rp_uiT, I_N, bsum);

    scan_pass1<<<nb_u, nthr, 0, stream>>>(rp_soc, U_N, bsum);
    scan_pass2<<<1, nthr, 0, stream>>>(bsum, nb_u);
    scan_pass3<<<nb_u, nthr, 0, stream>>>(rp_soc, U_N, bsum);

    // 4) scatters (after these, rp_* are "shifted": rp[r] = end of row r)
    scatter_k<<<(NNZ_UI + nthr - 1) / nthr, nthr, 0, stream>>>(ui_rows, ui_cols, ui_vals,
                                                              rp_ui, pairs_ui, NNZ_UI);
    scatter_k<<<(NNZ_UI + nthr - 1) / nthr, nthr, 0, stream>>>(ui_cols, ui_rows, ui_vals,
                                                              rp_uiT, pairs_uiT, NNZ_UI);
    scatter_k<<<(NNZ_SOC + nthr - 1) / nthr, nthr, 0, stream>>>(soc_rows, soc_cols, soc_vals,
                                                               rp_soc, pairs_soc, NNZ_SOC);

    // 5) ui_embs[0] = soc_embs[0] = user_emb
    copy2_f4<<<(int)(UD / 4 + nthr - 1) / nthr, nthr, 0, stream>>>(
        (const float4*)user_emb, (float4*)o_ui0, (float4*)o_s0, (int)(UD / 4));

    const int xl_u = U_N / 16;   // 6250
    const int xl_i = I_N / 16;   // 12500

    // 6) fused SpMM + transform + LN
    // UI layer 0
    spmm_xln<<<xl_u, nthr, 0, stream>>>(rp_ui, pairs_ui, item_emb, user_emb,
                                        ui_W, ui_b, ln_ui_g, ln_ui_b, o_ui1, U_N);
    spmm_xln<<<xl_i, nthr, 0, stream>>>(rp_uiT, pairs_uiT, user_emb, item_emb,
                                        ui_W, ui_b, ln_ui_g, ln_ui_b, o_ci, I_N);
    // UI layer 1 (ua first: it must read o_ci before ia overwrites it)
    spmm_xln<<<xl_u, nthr, 0, stream>>>(rp_ui, pairs_ui, o_ci, o_ui1,
                                        ui_W + 4096, ui_b + 64, ln_ui_g + 64, ln_ui_b + 64,
                                        o_ui2, U_N);
    spmm_xln<<<xl_i, nthr, 0, stream>>>(rp_uiT, pairs_uiT, o_ui1, o_ci,
                                        ui_W + 4096, ui_b + 64, ln_ui_g + 64, ln_ui_b + 64,
                                        o_ci, I_N);
    // Social layers
    spmm_xln<<<xl_u, nthr, 0, stream>>>(rp_soc, pairs_soc, user_emb, user_emb,
                                        soc_W, soc_b, ln_soc_g, ln_soc_b, o_s1, U_N);
    spmm_xln<<<xl_u, nthr, 0, stream>>>(rp_soc, pairs_soc, o_s1, o_s1,
                                        soc_W + 4096, soc_b + 64, ln_soc_g + 64, ln_soc_b + 64,
                                        o_s2, U_N);
}

// Round 3
// 1063.347 us; speedup vs baseline: 8.3041x; 1.1964x over previous
//
#include <hip/hip_runtime.h>

// Problem constants (match reference)
#define U_N 100000
#define I_N 200000
#define D   64
#define NNZ_UI 2000000
#define NNZ_SOC 1000000
#define LN_EPS 1e-5f
#define LSLOPE 0.01f
#define SCAN_CHUNK 1024   // elements per block in the scan (256 thr x 4)

__device__ __forceinline__ float bf2f(unsigned short h) {
    return __uint_as_float((unsigned int)h << 16);
}
__device__ __forceinline__ unsigned short f2bf(float f) {   // round-to-nearest-even
    unsigned int u = __float_as_uint(f);
    return (unsigned short)((u + 0x7FFFu + ((u >> 16) & 1u)) >> 16);
}

// ---------------------------------------------------------------------------
__global__ void zero_i4(int4* __restrict__ p, int n4) {
    int i = blockIdx.x * blockDim.x + threadIdx.x;
    if (i < n4) p[i] = make_int4(0, 0, 0, 0);
}

__global__ void copy2_f4(const float4* __restrict__ src, float4* __restrict__ d1,
                         float4* __restrict__ d2, int n4) {
    int i = blockIdx.x * blockDim.x + threadIdx.x;
    if (i < n4) {
        float4 v = src[i];
        d1[i] = v;
        d2[i] = v;
    }
}

__global__ void f32_to_bf16_k(const float4* __restrict__ src, ushort4* __restrict__ dst, int n4) {
    int i = blockIdx.x * blockDim.x + threadIdx.x;
    if (i < n4) {
        float4 v = src[i];
        ushort4 o;
        o.x = f2bf(v.x); o.y = f2bf(v.y); o.z = f2bf(v.z); o.w = f2bf(v.w);
        dst[i] = o;
    }
}

// ---------------------------------------------------------------------------
// CSR build: histogram -> exclusive scan -> partitioned scatter
// (rptr ends "shifted": rptr[r] == end of row r; start is rptr[r-1], 0 for r=0)

__global__ void hist4_k(const int4* __restrict__ rows4, int* __restrict__ cnt, int n4) {
    int i = blockIdx.x * blockDim.x + threadIdx.x;
    if (i < n4) {
        int4 v = rows4[i];
        atomicAdd(&cnt[v.x], 1);
        atomicAdd(&cnt[v.y], 1);
        atomicAdd(&cnt[v.z], 1);
        atomicAdd(&cnt[v.w], 1);
    }
}

__global__ __launch_bounds__(256) void scan_pass1(const int* __restrict__ cnt, int n,
                                                  int* __restrict__ bsum) {
    int base = blockIdx.x * SCAN_CHUNK + threadIdx.x * 4;
    int s = 0;
    #pragma unroll
    for (int q = 0; q < 4; ++q) {
        int idx = base + q;
        if (idx < n) s += cnt[idx];
    }
    #pragma unroll
    for (int m = 1; m < 64; m <<= 1) s += __shfl_xor(s, m, 64);
    __shared__ int ws[4];
    if ((threadIdx.x & 63) == 0) ws[threadIdx.x >> 6] = s;
    __syncthreads();
    if (threadIdx.x == 0) bsum[blockIdx.x] = ws[0] + ws[1] + ws[2] + ws[3];
}

__global__ __launch_bounds__(256) void scan_pass2(int* __restrict__ bsum, int nb) {
    int t = threadIdx.x;
    int v = (t < nb) ? bsum[t] : 0;
    int lane = t & 63, w = t >> 6;
    int x = v;
    #pragma unroll
    for (int m = 1; m < 64; m <<= 1) {
        int y = __shfl_up(x, m, 64);
        if (lane >= m) x += y;
    }
    __shared__ int wtot[4];
    if (lane == 63) wtot[w] = x;
    __syncthreads();
    int off = 0;
    for (int i = 0; i < w; ++i) off += wtot[i];
    if (t < nb) bsum[t] = (x + off) - v;   // exclusive
}

__global__ __launch_bounds__(256) void scan_pass3(int* __restrict__ cnt, int n,
                                                  const int* __restrict__ bsum) {
    int base = blockIdx.x * SCAN_CHUNK + threadIdx.x * 4;
    int v[4];
    int s = 0;
    #pragma unroll
    for (int q = 0; q < 4; ++q) {
        int idx = base + q;
        v[q] = (idx < n) ? cnt[idx] : 0;
        s += v[q];
    }
    int lane = threadIdx.x & 63, w = threadIdx.x >> 6;
    int x = s;
    #pragma unroll
    for (int m = 1; m < 64; m <<= 1) {
        int y = __shfl_up(x, m, 64);
        if (lane >= m) x += y;
    }
    __shared__ int wtot[4];
    if (lane == 63) wtot[w] = x;
    __syncthreads();
    int off = 0;
    for (int i = 0; i < w; ++i) off += wtot[i];
    int run = bsum[blockIdx.x] + (x - s) + off;
    #pragma unroll
    for (int q = 0; q < 4; ++q) {
        int idx = base + q;
        int t = v[q];
        if (idx < n) cnt[idx] = run;
        run += t;
    }
}

// Partitioned scatter: pass p only scatters edges whose row is in
// [p*span, (p+1)*span) so pairs writes cluster in a ~1MB region that stays
// resident in L2 while its lines fill (kills the 8x write amplification).
#define SCAT_EPT 8
__global__ __launch_bounds__(256) void scatter_part(
    const int* __restrict__ rows, const int* __restrict__ cols,
    const float* __restrict__ vals, int* __restrict__ rptr,
    int2* __restrict__ pairs, int nnz, int span, int nparts)
{
    int base = blockIdx.x * (256 * SCAT_EPT) + threadIdx.x;
    int lo = 0;
    for (int p = 0; p < nparts; ++p, lo += span) {
        #pragma unroll
        for (int k = 0; k < SCAT_EPT; ++k) {
            int i = base + k * 256;
            if (i < nnz) {
                int r = rows[i];
                if ((unsigned)(r - lo) < (unsigned)span) {
                    int pos = atomicAdd(&rptr[r], 1);
                    pairs[pos] = make_int2(cols[i], __float_as_int(vals[i]));
                }
            }
        }
    }
}

// ---------------------------------------------------------------------------
// Fused: agg = CSR-gather SpMM row; h = leaky_relu(agg @ W^T + b);
//        y = LN(cur + h)*gamma + beta.  Optionally bf16 gather source and
//        bf16 shadow output (for next layer's gather).
template<int SRC_BF, int OUT_BF>
__global__ __launch_bounds__(256) void spmm_xln(
    const int* __restrict__ rptr, const int2* __restrict__ pairs,
    const void* __restrict__ xsrc, const float* __restrict__ cur,
    const float* __restrict__ W, const float* __restrict__ bias,
    const float* __restrict__ gamma, const float* __restrict__ beta,
    float* __restrict__ dst, unsigned short* __restrict__ dst_bf, int n)
{
    __shared__ float Wt[64][65];
    __shared__ float arow[4][64][4];

    for (int i = threadIdx.x; i < 4096; i += 256)
        Wt[i & 63][i >> 6] = W[i];

    const int lane = threadIdx.x & 63;
    const int grp  = threadIdx.x >> 6;
    const int rb   = blockIdx.x * 16 + grp * 4;
    const int r    = lane >> 4;
    const int sub  = lane & 15;
    const int row  = rb + r;

    float4 acc  = make_float4(0.f, 0.f, 0.f, 0.f);
    float4 acc2 = make_float4(0.f, 0.f, 0.f, 0.f);
    {
        int start = (row == 0) ? 0 : rptr[row - 1];
        int end   = rptr[row];
        const float* xf = (const float*)xsrc;
        const unsigned short* xb = (const unsigned short*)xsrc;
        int e = start;
        for (; e + 2 <= end; e += 2) {
            int2 p0 = pairs[e];
            int2 p1 = pairs[e + 1];
            float v0 = __int_as_float(p0.y);
            float v1 = __int_as_float(p1.y);
            if (SRC_BF) {
                ushort4 q0 = *(const ushort4*)(xb + (size_t)p0.x * D + sub * 4);
                ushort4 q1 = *(const ushort4*)(xb + (size_t)p1.x * D + sub * 4);
                acc.x  += v0 * bf2f(q0.x); acc.y  += v0 * bf2f(q0.y);
                acc.z  += v0 * bf2f(q0.z); acc.w  += v0 * bf2f(q0.w);
                acc2.x += v1 * bf2f(q1.x); acc2.y += v1 * bf2f(q1.y);
                acc2.z += v1 * bf2f(q1.z); acc2.w += v1 * bf2f(q1.w);
            } else {
                float4 x0 = *(const float4*)(xf + (size_t)p0.x * D + sub * 4);
                float4 x1 = *(const float4*)(xf + (size_t)p1.x * D + sub * 4);
                acc.x  += v0 * x0.x; acc.y  += v0 * x0.y;
                acc.z  += v0 * x0.z; acc.w  += v0 * x0.w;
                acc2.x += v1 * x1.x; acc2.y += v1 * x1.y;
                acc2.z += v1 * x1.z; acc2.w += v1 * x1.w;
            }
        }
        if (e < end) {
            int2 p0 = pairs[e];
            float v0 = __int_as_float(p0.y);
            if (SRC_BF) {
                ushort4 q0 = *(const ushort4*)(xb + (size_t)p0.x * D + sub * 4);
                acc.x += v0 * bf2f(q0.x); acc.y += v0 * bf2f(q0.y);
                acc.z += v0 * bf2f(q0.z); acc.w += v0 * bf2f(q0.w);
            } else {
                float4 x0 = *(const float4*)(xf + (size_t)p0.x * D + sub * 4);
                acc.x += v0 * x0.x; acc.y += v0 * x0.y;
                acc.z += v0 * x0.z; acc.w += v0 * x0.w;
            }
        }
    }
    acc.x += acc2.x; acc.y += acc2.y; acc.z += acc2.z; acc.w += acc2.w;

    arow[grp][sub * 4 + 0][r] = acc.x;
    arow[grp][sub * 4 + 1][r] = acc.y;
    arow[grp][sub * 4 + 2][r] = acc.z;
    arow[grp][sub * 4 + 3][r] = acc.w;
    __syncthreads();

    float h0 = 0.f, h1 = 0.f, h2 = 0.f, h3 = 0.f;
    #pragma unroll
    for (int k = 0; k < 64; ++k) {
        float w  = Wt[k][lane];
        float4 a = *(const float4*)&arow[grp][k][0];
        h0 += w * a.x; h1 += w * a.y; h2 += w * a.z; h3 += w * a.w;
    }

    const float bj  = bias[lane];
    const float gj  = gamma[lane];
    const float bej = beta[lane];

    float hr[4] = {h0, h1, h2, h3};
    #pragma unroll
    for (int rr = 0; rr < 4; ++rr) {
        float h = hr[rr] + bj;
        h = h > 0.f ? h : LSLOPE * h;
        float xv = cur[(size_t)(rb + rr) * D + lane] + h;
        float s = xv, s2 = xv * xv;
        #pragma unroll
        for (int m = 32; m >= 1; m >>= 1) {
            s  += __shfl_xor(s, m, 64);
            s2 += __shfl_xor(s2, m, 64);
        }
        float mean = s * (1.f / 64.f);
        float var  = s2 * (1.f / 64.f) - mean * mean;
        float y = (xv - mean) * rsqrtf(var + LN_EPS) * gj + bej;
        dst[(size_t)(rb + rr) * D + lane] = y;
        if (OUT_BF) dst_bf[(size_t)(rb + rr) * D + lane] = f2bf(y);
    }
}

// ---------------------------------------------------------------------------
extern "C" void kernel_launch(void* const* d_in, const int* in_sizes, int n_in,
                              void* d_out, int out_size, void* d_ws, size_t ws_size,
                              hipStream_t stream)
{
    const float* user_emb = (const float*)d_in[0];
    const float* item_emb = (const float*)d_in[1];
    const int*   ui_rows  = (const int*)d_in[2];
    const int*   ui_cols  = (const int*)d_in[3];
    const float* ui_vals  = (const float*)d_in[4];
    const int*   soc_rows = (const int*)d_in[5];
    const int*   soc_cols = (const int*)d_in[6];
    const float* soc_vals = (const float*)d_in[7];
    const float* ui_W     = (const float*)d_in[8];
    const float* ui_b     = (const float*)d_in[9];
    const float* soc_W    = (const float*)d_in[10];
    const float* soc_b    = (const float*)d_in[11];
    const float* ln_ui_g  = (const float*)d_in[12];
    const float* ln_ui_b  = (const float*)d_in[13];
    const float* ln_soc_g = (const float*)d_in[14];
    const float* ln_soc_b = (const float*)d_in[15];

    float* out = (float*)d_out;
    const size_t UD = (size_t)U_N * D;
    const size_t ID = (size_t)I_N * D;

    float* o_ui0 = out;
    float* o_ui1 = out + UD;
    float* o_ui2 = out + 2 * UD;
    float* o_s0  = out + 3 * UD;
    float* o_s1  = out + 4 * UD;
    float* o_s2  = out + 5 * UD;
    float* o_ci  = out + 6 * UD;   // item intermediate + final

    // workspace layout
    int2* pairs_ui  = (int2*)d_ws;                    // 2M
    int2* pairs_uiT = pairs_ui + NNZ_UI;              // 2M
    int2* pairs_soc = pairs_uiT + NNZ_UI;             // 1M
    int*  rp_ui     = (int*)(pairs_soc + NNZ_SOC);    // U
    int*  rp_uiT    = rp_ui + U_N;                    // I
    int*  rp_soc    = rp_uiT + I_N;                   // U
    int*  bsum      = rp_soc + U_N;                   // 256
    unsigned short* bfA = (unsigned short*)(bsum + 256);  // user_bf            [U*D]
    unsigned short* bfB = bfA + UD;                       // item_bf -> ci_bf   [I*D]
    unsigned short* bfC = bfB + ID;                       // cu1_bf -> cs1_bf   [U*D]

    const size_t need_bf = (size_t)(bfC + UD) - (size_t)d_ws;
    const bool use_bf = ws_size >= need_bf;

    const int nthr = 256;
    const int nb_u = (U_N + SCAN_CHUNK - 1) / SCAN_CHUNK;   // 98
    const int nb_i = (I_N + SCAN_CHUNK - 1) / SCAN_CHUNK;   // 196

    // 1) zero the 3 count arrays (contiguous: U + I + U ints)
    {
        int ntot = U_N + I_N + U_N;
        zero_i4<<<(ntot / 4 + nthr - 1) / nthr, nthr, 0, stream>>>((int4*)rp_ui, ntot / 4);
    }

    // 2) histograms (int4 reads)
    hist4_k<<<(NNZ_UI / 4 + nthr - 1) / nthr, nthr, 0, stream>>>((const int4*)ui_rows, rp_ui, NNZ_UI / 4);
    hist4_k<<<(NNZ_UI / 4 + nthr - 1) / nthr, nthr, 0, stream>>>((const int4*)ui_cols, rp_uiT, NNZ_UI / 4);
    hist4_k<<<(NNZ_SOC / 4 + nthr - 1) / nthr, nthr, 0, stream>>>((const int4*)soc_rows, rp_soc, NNZ_SOC / 4);

    // 3) exclusive scans
    scan_pass1<<<nb_u, nthr, 0, stream>>>(rp_ui, U_N, bsum);
    scan_pass2<<<1, nthr, 0, stream>>>(bsum, nb_u);
    scan_pass3<<<nb_u, nthr, 0, stream>>>(rp_ui, U_N, bsum);

    scan_pass1<<<nb_i, nthr, 0, stream>>>(rp_uiT, I_N, bsum);
    scan_pass2<<<1, nthr, 0, stream>>>(bsum, nb_i);
    scan_pass3<<<nb_i, nthr, 0, stream>>>(rp_uiT, I_N, bsum);

    scan_pass1<<<nb_u, nthr, 0, stream>>>(rp_soc, U_N, bsum);
    scan_pass2<<<1, nthr, 0, stream>>>(bsum, nb_u);
    scan_pass3<<<nb_u, nthr, 0, stream>>>(rp_soc, U_N, bsum);

    // 4) partitioned scatters (after these, rp_* are shifted: rp[r]=end of row r)
    {
        int gb_ui  = (NNZ_UI  + 256 * SCAT_EPT - 1) / (256 * SCAT_EPT);
        int gb_soc = (NNZ_SOC + 256 * SCAT_EPT - 1) / (256 * SCAT_EPT);
        scatter_part<<<gb_ui, nthr, 0, stream>>>(ui_rows, ui_cols, ui_vals,
                                                 rp_ui, pairs_ui, NNZ_UI, (U_N + 15) / 16, 16);
        scatter_part<<<gb_ui, nthr, 0, stream>>>(ui_cols, ui_rows, ui_vals,
                                                 rp_uiT, pairs_uiT, NNZ_UI, (I_N + 15) / 16, 16);
        scatter_part<<<gb_soc, nthr, 0, stream>>>(soc_rows, soc_cols, soc_vals,
                                                  rp_soc, pairs_soc, NNZ_SOC, (U_N + 7) / 8, 8);
    }

    // 5) ui_embs[0] = soc_embs[0] = user_emb
    copy2_f4<<<(int)(UD / 4 + nthr - 1) / nthr, nthr, 0, stream>>>(
        (const float4*)user_emb, (float4*)o_ui0, (float4*)o_s0, (int)(UD / 4));

    const int xl_u = U_N / 16;   // 6250
    const int xl_i = I_N / 16;   // 12500

    if (use_bf) {
        // bf16 shadows of the gather sources
        f32_to_bf16_k<<<(int)(UD / 4 + nthr - 1) / nthr, nthr, 0, stream>>>(
            (const float4*)user_emb, (ushort4*)bfA, (int)(UD / 4));
        f32_to_bf16_k<<<(int)(ID / 4 + nthr - 1) / nthr, nthr, 0, stream>>>(
            (const float4*)item_emb, (ushort4*)bfB, (int)(ID / 4));

        // UI layer 0: user<-items (src bfB), item<-users (src bfA)
        spmm_xln<1, 1><<<xl_u, nthr, 0, stream>>>(rp_ui, pairs_ui, bfB, user_emb,
            ui_W, ui_b, ln_ui_g, ln_ui_b, o_ui1, bfC, U_N);                 // cu1 -> bfC
        spmm_xln<1, 1><<<xl_i, nthr, 0, stream>>>(rp_uiT, pairs_uiT, bfA, item_emb,
            ui_W, ui_b, ln_ui_g, ln_ui_b, o_ci, bfB, I_N);                  // ci  -> bfB (item_bf dead)
        // UI layer 1 (ua first: reads ci before item-side overwrites o_ci)
        spmm_xln<1, 0><<<xl_u, nthr, 0, stream>>>(rp_ui, pairs_ui, bfB, o_ui1,
            ui_W + 4096, ui_b + 64, ln_ui_g + 64, ln_ui_b + 64, o_ui2, nullptr, U_N);
        spmm_xln<1, 0><<<xl_i, nthr, 0, stream>>>(rp_uiT, pairs_uiT, bfC, o_ci,
            ui_W + 4096, ui_b + 64, ln_ui_g + 64, ln_ui_b + 64, o_ci, nullptr, I_N);
        // Social layers (bfC free after uiT-l1)
        spmm_xln<1, 1><<<xl_u, nthr, 0, stream>>>(rp_soc, pairs_soc, bfA, user_emb,
            soc_W, soc_b, ln_soc_g, ln_soc_b, o_s1, bfC, U_N);              // cs1 -> bfC
        spmm_xln<1, 0><<<xl_u, nthr, 0, stream>>>(rp_soc, pairs_soc, bfC, o_s1,
            soc_W + 4096, soc_b + 64, ln_soc_g + 64, ln_soc_b + 64, o_s2, nullptr, U_N);
    } else {
        // f32 fallback
        spmm_xln<0, 0><<<xl_u, nthr, 0, stream>>>(rp_ui, pairs_ui, item_emb, user_emb,
            ui_W, ui_b, ln_ui_g, ln_ui_b, o_ui1, nullptr, U_N);
        spmm_xln<0, 0><<<xl_i, nthr, 0, stream>>>(rp_uiT, pairs_uiT, user_emb, item_emb,
            ui_W, ui_b, ln_ui_g, ln_ui_b, o_ci, nullptr, I_N);
        spmm_xln<0, 0><<<xl_u, nthr, 0, stream>>>(rp_ui, pairs_ui, o_ci, o_ui1,
            ui_W + 4096, ui_b + 64, ln_ui_g + 64, ln_ui_b + 64, o_ui2, nullptr, U_N);
        spmm_xln<0, 0><<<xl_i, nthr, 0, stream>>>(rp_uiT, pairs_uiT, o_ui1, o_ci,
            ui_W + 4096, ui_b + 64, ln_ui_g + 64, ln_ui_b + 64, o_ci, nullptr, I_N);
        spmm_xln<0, 0><<<xl_u, nthr, 0, stream>>>(rp_soc, pairs_soc, user_emb, user_emb,
            soc_W, soc_b, ln_soc_g, ln_soc_b, o_s1, nullptr, U_N);
        spmm_xln<0, 0><<<xl_u, nthr, 0, stream>>>(rp_soc, pairs_soc, o_s1, o_s1,
            soc_W + 4096, soc_b + 64, ln_soc_g + 64, ln_soc_b + 64, o_s2, nullptr, U_N);
    }
}

// Round 4
// 855.141 us; speedup vs baseline: 10.3260x; 1.2435x over previous
//
#include <hip/hip_runtime.h>

#define U_N 100000
#define I_N 200000
#define D   64
#define NNZ_UI 2000000
#define NNZ_SOC 1000000
#define LN_EPS 1e-5f
#define LSLOPE 0.01f
#define SCAN_CHUNK 1024
#define SCAT_EPT 8

using short8 = __attribute__((ext_vector_type(8))) short;
using f32x4  = __attribute__((ext_vector_type(4))) float;

__device__ __forceinline__ float bf2f(unsigned short h) {
    return __uint_as_float((unsigned int)h << 16);
}
__device__ __forceinline__ unsigned short f2bf(float f) {   // RNE
    unsigned int u = __float_as_uint(f);
    return (unsigned short)((u + 0x7FFFu + ((u >> 16) & 1u)) >> 16);
}

// ---------------------------------------------------------------------------
__global__ void zero_i4(int4* __restrict__ p, int n4) {
    int i = blockIdx.x * blockDim.x + threadIdx.x;
    if (i < n4) p[i] = make_int4(0, 0, 0, 0);
}

__global__ void copy2_f4(const float4* __restrict__ src, float4* __restrict__ d1,
                         float4* __restrict__ d2, int n4) {
    int i = blockIdx.x * blockDim.x + threadIdx.x;
    if (i < n4) {
        float4 v = src[i];
        d1[i] = v;
        d2[i] = v;
    }
}

// convert ui_W (8192 f32) then soc_W (8192 f32) into contiguous bf16
__global__ void wbf_k(const float* __restrict__ wa, const float* __restrict__ wb,
                      unsigned short* __restrict__ dst) {
    int i = blockIdx.x * blockDim.x + threadIdx.x;   // grid covers 16384
    float v = (i < 8192) ? wa[i] : wb[i - 8192];
    dst[i] = f2bf(v);
}

// ---------------------------------------------------------------------------
// merged histogram (int4 reads)
struct HistArgs {
    const int4* rows4[3];
    int* cnt[3];
    int n4[3];
    int base[4];
};
__global__ __launch_bounds__(256) void hist_m(HistArgs a) {
    int b = blockIdx.x;
    int si = (b >= a.base[1]) + (b >= a.base[2]);
    int i = (b - a.base[si]) * 256 + threadIdx.x;
    if (i < a.n4[si]) {
        int4 v = a.rows4[si][i];
        int* c = a.cnt[si];
        atomicAdd(&c[v.x], 1);
        atomicAdd(&c[v.y], 1);
        atomicAdd(&c[v.z], 1);
        atomicAdd(&c[v.w], 1);
    }
}

// merged scans -------------------------------------------------------------
struct ScanArgs {
    int* cnt[3];
    int n[3];
    int off[3];    // bsum offsets
    int nb[3];
    int base[4];   // block bases for pass1/pass3
};

__global__ __launch_bounds__(256) void scan_p1(ScanArgs a, int* __restrict__ bsum) {
    int b = blockIdx.x;
    int si = (b >= a.base[1]) + (b >= a.base[2]);
    int lb = b - a.base[si];
    const int* cnt = a.cnt[si];
    int n = a.n[si];
    int bs = lb * SCAN_CHUNK + threadIdx.x * 4;
    int s = 0;
    #pragma unroll
    for (int q = 0; q < 4; ++q) {
        int idx = bs + q;
        if (idx < n) s += cnt[idx];
    }
    #pragma unroll
    for (int m = 1; m < 64; m <<= 1) s += __shfl_xor(s, m, 64);
    __shared__ int ws[4];
    if ((threadIdx.x & 63) == 0) ws[threadIdx.x >> 6] = s;
    __syncthreads();
    if (threadIdx.x == 0) bsum[a.off[si] + lb] = ws[0] + ws[1] + ws[2] + ws[3];
}

__global__ __launch_bounds__(256) void scan_p2(ScanArgs a, int* __restrict__ bsum) {
    int si = blockIdx.x;
    int nb = a.nb[si];
    int* bp = bsum + a.off[si];
    int t = threadIdx.x;
    int v = (t < nb) ? bp[t] : 0;
    int lane = t & 63, w = t >> 6;
    int x = v;
    #pragma unroll
    for (int m = 1; m < 64; m <<= 1) {
        int y = __shfl_up(x, m, 64);
        if (lane >= m) x += y;
    }
    __shared__ int wtot[4];
    if (lane == 63) wtot[w] = x;
    __syncthreads();
    int off = 0;
    for (int i = 0; i < w; ++i) off += wtot[i];
    if (t < nb) bp[t] = (x + off) - v;
}

__global__ __launch_bounds__(256) void scan_p3(ScanArgs a, const int* __restrict__ bsum) {
    int b = blockIdx.x;
    int si = (b >= a.base[1]) + (b >= a.base[2]);
    int lb = b - a.base[si];
    int* cnt = a.cnt[si];
    int n = a.n[si];
    int bs = lb * SCAN_CHUNK + threadIdx.x * 4;
    int v[4];
    int s = 0;
    #pragma unroll
    for (int q = 0; q < 4; ++q) {
        int idx = bs + q;
        v[q] = (idx < n) ? cnt[idx] : 0;
        s += v[q];
    }
    int lane = threadIdx.x & 63, w = threadIdx.x >> 6;
    int x = s;
    #pragma unroll
    for (int m = 1; m < 64; m <<= 1) {
        int y = __shfl_up(x, m, 64);
        if (lane >= m) x += y;
    }
    __shared__ int wtot[4];
    if (lane == 63) wtot[w] = x;
    __syncthreads();
    int off = 0;
    for (int i = 0; i < w; ++i) off += wtot[i];
    int run = bsum[a.off[si] + lb] + (x - s) + off;
    #pragma unroll
    for (int q = 0; q < 4; ++q) {
        int idx = bs + q;
        int t = v[q];
        if (idx < n) cnt[idx] = run;
        run += t;
    }
}

// merged partitioned scatter -----------------------------------------------
struct ScatArgs {
    const int* rows[3];
    const int* cols[3];
    const float* vals[3];
    int* rptr[3];
    int2* pairs[3];
    int nnz[3];
    int span[3];
    int nparts[3];
    int base[4];
};
__global__ __launch_bounds__(256) void scatter_m(ScatArgs a) {
    int b = blockIdx.x;
    int si = (b >= a.base[1]) + (b >= a.base[2]);
    int lb = b - a.base[si];
    const int* rows = a.rows[si];
    const int* cols = a.cols[si];
    const float* vals = a.vals[si];
    int* rptr = a.rptr[si];
    int2* pairs = a.pairs[si];
    const int nnz = a.nnz[si], span = a.span[si], nparts = a.nparts[si];
    int bs = lb * (256 * SCAT_EPT) + threadIdx.x;
    int lo = 0;
    for (int p = 0; p < nparts; ++p, lo += span) {
        #pragma unroll
        for (int k = 0; k < SCAT_EPT; ++k) {
            int i = bs + k * 256;
            if (i < nnz) {
                int r = rows[i];
                if ((unsigned)(r - lo) < (unsigned)span) {
                    int pos = atomicAdd(&rptr[r], 1);
                    pairs[pos] = make_int2(cols[i], __float_as_int(vals[i]));
                }
            }
        }
    }
}

// ---------------------------------------------------------------------------
// MFMA transform: dst_bf16[n,64] = src_f32[n,64] @ W^T  (W given as bf16 rows)
// Wave handles 16 rows; block = 4 waves = 64 rows. No LDS.
struct XfArgs {
    const float* src[3];
    const unsigned short* wbf[3];   // [64][64] bf16, row j = W[j][*]
    unsigned short* dst[3];
    int n[3];
    int base[4];
};
__global__ __launch_bounds__(256) void xform_mfma(XfArgs a) {
    int b = blockIdx.x;
    int si = (b >= a.base[1]) + (b >= a.base[2]);
    const float* src = a.src[si];
    const unsigned short* wb = a.wbf[si];
    unsigned short* dst = a.dst[si];
    const int n = a.n[si];

    const int lane = threadIdx.x & 63;
    const int wv   = threadIdx.x >> 6;
    const int rbw  = (b - a.base[si]) * 64 + wv * 16;
    const int m = lane & 15, g = lane >> 4;

    f32x4 acc0 = {0.f, 0.f, 0.f, 0.f};
    f32x4 acc1 = acc0, acc2 = acc0, acc3 = acc0;

    const int arow = min(rbw + m, n - 1);            // clamp (OOB rows unused)
    const float* xp = src + (size_t)arow * D + g * 8;
    const unsigned short* wp0 = wb + (size_t)m * D + g * 8;

    #pragma unroll
    for (int t = 0; t < 2; ++t) {
        float4 a0 = *(const float4*)(xp + t * 32);
        float4 a1 = *(const float4*)(xp + t * 32 + 4);
        short8 af;
        af[0] = (short)f2bf(a0.x); af[1] = (short)f2bf(a0.y);
        af[2] = (short)f2bf(a0.z); af[3] = (short)f2bf(a0.w);
        af[4] = (short)f2bf(a1.x); af[5] = (short)f2bf(a1.y);
        af[6] = (short)f2bf(a1.z); af[7] = (short)f2bf(a1.w);
        const unsigned short* wp = wp0 + t * 32;
        short8 b0 = *(const short8*)(wp);
        short8 b1 = *(const short8*)(wp + 16 * D);
        short8 b2 = *(const short8*)(wp + 32 * D);
        short8 b3 = *(const short8*)(wp + 48 * D);
        acc0 = __builtin_amdgcn_mfma_f32_16x16x32_bf16(af, b0, acc0, 0, 0, 0);
        acc1 = __builtin_amdgcn_mfma_f32_16x16x32_bf16(af, b1, acc1, 0, 0, 0);
        acc2 = __builtin_amdgcn_mfma_f32_16x16x32_bf16(af, b2, acc2, 0, 0, 0);
        acc3 = __builtin_amdgcn_mfma_f32_16x16x32_bf16(af, b3, acc3, 0, 0, 0);
    }

    #pragma unroll
    for (int reg = 0; reg < 4; ++reg) {
        int orow = rbw + g * 4 + reg;
        if (orow < n) {
            size_t o = (size_t)orow * D + m;
            dst[o]      = f2bf(acc0[reg]);
            dst[o + 16] = f2bf(acc1[reg]);
            dst[o + 32] = f2bf(acc2[reg]);
            dst[o + 48] = f2bf(acc3[reg]);
        }
    }
}

// ---------------------------------------------------------------------------
// Light SpMM + epilogue: agg = sum val*Y[col]; h = leaky(agg + b);
// y = LN(cur + h)*g + be.  16 lanes/row, 4 rows/wave, 16 rows/block. No LDS.
struct SpArgs {
    const int* rptr[3];
    const int2* pairs[3];
    const unsigned short* y[3];
    const float* cur[3];
    const float* bias[3];
    const float* gamma[3];
    const float* beta[3];
    float* dst[3];
    int base[4];
};
__global__ __launch_bounds__(256) void spmm_ln(SpArgs a) {
    int b = blockIdx.x;
    int si = (b >= a.base[1]) + (b >= a.base[2]);
    const int* rptr = a.rptr[si];
    const int2* pairs = a.pairs[si];
    const unsigned short* y = a.y[si];

    const int lane = threadIdx.x & 63;
    const int wv   = threadIdx.x >> 6;
    const int r = lane >> 4, sub = lane & 15;
    const int row = (b - a.base[si]) * 16 + wv * 4 + r;

    const int start = (row == 0) ? 0 : rptr[row - 1];
    const int end   = rptr[row];

    float4 acc  = make_float4(0.f, 0.f, 0.f, 0.f);
    float4 acc2 = make_float4(0.f, 0.f, 0.f, 0.f);
    int e = start;
    for (; e + 2 <= end; e += 2) {
        int2 p0 = pairs[e];
        int2 p1 = pairs[e + 1];
        float v0 = __int_as_float(p0.y);
        float v1 = __int_as_float(p1.y);
        ushort4 q0 = *(const ushort4*)(y + (size_t)p0.x * D + sub * 4);
        ushort4 q1 = *(const ushort4*)(y + (size_t)p1.x * D + sub * 4);
        acc.x  += v0 * bf2f(q0.x); acc.y  += v0 * bf2f(q0.y);
        acc.z  += v0 * bf2f(q0.z); acc.w  += v0 * bf2f(q0.w);
        acc2.x += v1 * bf2f(q1.x); acc2.y += v1 * bf2f(q1.y);
        acc2.z += v1 * bf2f(q1.z); acc2.w += v1 * bf2f(q1.w);
    }
    if (e < end) {
        int2 p0 = pairs[e];
        float v0 = __int_as_float(p0.y);
        ushort4 q0 = *(const ushort4*)(y + (size_t)p0.x * D + sub * 4);
        acc.x += v0 * bf2f(q0.x); acc.y += v0 * bf2f(q0.y);
        acc.z += v0 * bf2f(q0.z); acc.w += v0 * bf2f(q0.w);
    }
    acc.x += acc2.x; acc.y += acc2.y; acc.z += acc2.z; acc.w += acc2.w;

    // epilogue
    float4 bi = *(const float4*)(a.bias[si] + sub * 4);
    float4 h;
    h.x = acc.x + bi.x; h.y = acc.y + bi.y; h.z = acc.z + bi.z; h.w = acc.w + bi.w;
    h.x = h.x > 0.f ? h.x : LSLOPE * h.x;
    h.y = h.y > 0.f ? h.y : LSLOPE * h.y;
    h.z = h.z > 0.f ? h.z : LSLOPE * h.z;
    h.w = h.w > 0.f ? h.w : LSLOPE * h.w;
    float4 cu = *(const float4*)(a.cur[si] + (size_t)row * D + sub * 4);
    float4 x;
    x.x = cu.x + h.x; x.y = cu.y + h.y; x.z = cu.z + h.z; x.w = cu.w + h.w;

    float s  = x.x + x.y + x.z + x.w;
    float s2 = x.x * x.x + x.y * x.y + x.z * x.z + x.w * x.w;
    #pragma unroll
    for (int m = 8; m >= 1; m >>= 1) {
        s  += __shfl_xor(s, m, 64);
        s2 += __shfl_xor(s2, m, 64);
    }
    float mean = s * (1.f / 64.f);
    float var  = s2 * (1.f / 64.f) - mean * mean;
    float rstd = rsqrtf(var + LN_EPS);

    float4 g4  = *(const float4*)(a.gamma[si] + sub * 4);
    float4 be4 = *(const float4*)(a.beta[si]  + sub * 4);
    float4 o;
    o.x = (x.x - mean) * rstd * g4.x + be4.x;
    o.y = (x.y - mean) * rstd * g4.y + be4.y;
    o.z = (x.z - mean) * rstd * g4.z + be4.z;
    o.w = (x.w - mean) * rstd * g4.w + be4.w;
    *(float4*)(a.dst[si] + (size_t)row * D + sub * 4) = o;
}

// ---------------------------------------------------------------------------
extern "C" void kernel_launch(void* const* d_in, const int* in_sizes, int n_in,
                              void* d_out, int out_size, void* d_ws, size_t ws_size,
                              hipStream_t stream)
{
    const float* user_emb = (const float*)d_in[0];
    const float* item_emb = (const float*)d_in[1];
    const int*   ui_rows  = (const int*)d_in[2];
    const int*   ui_cols  = (const int*)d_in[3];
    const float* ui_vals  = (const float*)d_in[4];
    const int*   soc_rows = (const int*)d_in[5];
    const int*   soc_cols = (const int*)d_in[6];
    const float* soc_vals = (const float*)d_in[7];
    const float* ui_W     = (const float*)d_in[8];
    const float* ui_b     = (const float*)d_in[9];
    const float* soc_W    = (const float*)d_in[10];
    const float* soc_b    = (const float*)d_in[11];
    const float* ln_ui_g  = (const float*)d_in[12];
    const float* ln_ui_b  = (const float*)d_in[13];
    const float* ln_soc_g = (const float*)d_in[14];
    const float* ln_soc_b = (const float*)d_in[15];

    float* out = (float*)d_out;
    const size_t UD = (size_t)U_N * D;
    const size_t ID = (size_t)I_N * D;

    float* o_ui0 = out;
    float* o_ui1 = out + UD;
    float* o_ui2 = out + 2 * UD;
    float* o_s0  = out + 3 * UD;
    float* o_s1  = out + 4 * UD;
    float* o_s2  = out + 5 * UD;
    float* o_ci  = out + 6 * UD;

    // workspace layout (~92.9 MB; proven capacity >= 93.7 MB from round 3)
    int2* pairs_ui  = (int2*)d_ws;                       // 16 MB
    int2* pairs_uiT = pairs_ui + NNZ_UI;                 // 16 MB
    int2* pairs_soc = pairs_uiT + NNZ_UI;                // 8 MB
    int*  rp_ui     = (int*)(pairs_soc + NNZ_SOC);       // U
    int*  rp_uiT    = rp_ui + U_N;                       // I
    int*  rp_soc    = rp_uiT + I_N;                      // U
    int*  bsum      = rp_soc + U_N;                      // 512
    unsigned short* wbf = (unsigned short*)(bsum + 512); // 4 x 4096 bf16
    unsigned short* Yi  = wbf + 4 * 4096;                // I*D bf16 (25.6 MB)
    unsigned short* Yu  = Yi + ID;                       // U*D bf16 (12.8 MB)
    unsigned short* Ys  = Yu + UD;                       // U*D bf16 (12.8 MB)

    const unsigned short* wbfUI0 = wbf;
    const unsigned short* wbfUI1 = wbf + 4096;
    const unsigned short* wbfS0  = wbf + 8192;
    const unsigned short* wbfS1  = wbf + 12288;

    const int nthr = 256;

    // 1) zero count arrays (U + I + U contiguous)
    {
        int ntot = U_N + I_N + U_N;
        zero_i4<<<(ntot / 4 + nthr - 1) / nthr, nthr, 0, stream>>>((int4*)rp_ui, ntot / 4);
    }

    // 2) weights to bf16
    wbf_k<<<64, nthr, 0, stream>>>(ui_W, soc_W, wbf);

    // 3) merged histogram
    {
        HistArgs ha;
        ha.rows4[0] = (const int4*)ui_rows;  ha.cnt[0] = rp_ui;  ha.n4[0] = NNZ_UI / 4;
        ha.rows4[1] = (const int4*)ui_cols;  ha.cnt[1] = rp_uiT; ha.n4[1] = NNZ_UI / 4;
        ha.rows4[2] = (const int4*)soc_rows; ha.cnt[2] = rp_soc; ha.n4[2] = NNZ_SOC / 4;
        int g0 = (ha.n4[0] + nthr - 1) / nthr, g1 = (ha.n4[1] + nthr - 1) / nthr,
            g2 = (ha.n4[2] + nthr - 1) / nthr;
        ha.base[0] = 0; ha.base[1] = g0; ha.base[2] = g0 + g1; ha.base[3] = g0 + g1 + g2;
        hist_m<<<ha.base[3], nthr, 0, stream>>>(ha);
    }

    // 4) merged scans
    ScanArgs sa;
    {
        sa.cnt[0] = rp_ui;  sa.n[0] = U_N;
        sa.cnt[1] = rp_uiT; sa.n[1] = I_N;
        sa.cnt[2] = rp_soc; sa.n[2] = U_N;
        int nb0 = (U_N + SCAN_CHUNK - 1) / SCAN_CHUNK;   // 98
        int nb1 = (I_N + SCAN_CHUNK - 1) / SCAN_CHUNK;   // 196
        int nb2 = nb0;
        sa.nb[0] = nb0; sa.nb[1] = nb1; sa.nb[2] = nb2;
        sa.off[0] = 0; sa.off[1] = nb0; sa.off[2] = nb0 + nb1;
        sa.base[0] = 0; sa.base[1] = nb0; sa.base[2] = nb0 + nb1; sa.base[3] = nb0 + nb1 + nb2;
        scan_p1<<<sa.base[3], nthr, 0, stream>>>(sa, bsum);
        scan_p2<<<3, nthr, 0, stream>>>(sa, bsum);
        scan_p3<<<sa.base[3], nthr, 0, stream>>>(sa, bsum);
    }

    // 5) merged partitioned scatter
    {
        ScatArgs ca;
        ca.rows[0] = ui_rows;  ca.cols[0] = ui_cols;  ca.vals[0] = ui_vals;
        ca.rptr[0] = rp_ui;   ca.pairs[0] = pairs_ui;  ca.nnz[0] = NNZ_UI;
        ca.span[0] = (U_N + 15) / 16; ca.nparts[0] = 16;
        ca.rows[1] = ui_cols;  ca.cols[1] = ui_rows;  ca.vals[1] = ui_vals;
        ca.rptr[1] = rp_uiT;  ca.pairs[1] = pairs_uiT; ca.nnz[1] = NNZ_UI;
        ca.span[1] = (I_N + 15) / 16; ca.nparts[1] = 16;
        ca.rows[2] = soc_rows; ca.cols[2] = soc_cols; ca.vals[2] = soc_vals;
        ca.rptr[2] = rp_soc;  ca.pairs[2] = pairs_soc; ca.nnz[2] = NNZ_SOC;
        ca.span[2] = (U_N + 7) / 8; ca.nparts[2] = 8;
        int g0 = (NNZ_UI + 256 * SCAT_EPT - 1) / (256 * SCAT_EPT);
        int g2 = (NNZ_SOC + 256 * SCAT_EPT - 1) / (256 * SCAT_EPT);
        ca.base[0] = 0; ca.base[1] = g0; ca.base[2] = 2 * g0; ca.base[3] = 2 * g0 + g2;
        scatter_m<<<ca.base[3], nthr, 0, stream>>>(ca);
    }

    // 6) copy user_emb to output slots
    copy2_f4<<<(int)(UD / 4 + nthr - 1) / nthr, nthr, 0, stream>>>(
        (const float4*)user_emb, (float4*)o_ui0, (float4*)o_s0, (int)(UD / 4));

    const int xb_i = (I_N + 63) / 64;   // 3125
    const int xb_u = (U_N + 63) / 64;   // 1563

    // 7) T0: Yi=T(item,W0ui), Yu=T(user,W0ui), Ys=T(user,W0soc)
    {
        XfArgs xa;
        xa.src[0] = item_emb; xa.wbf[0] = wbfUI0; xa.dst[0] = Yi; xa.n[0] = I_N;
        xa.src[1] = user_emb; xa.wbf[1] = wbfUI0; xa.dst[1] = Yu; xa.n[1] = U_N;
        xa.src[2] = user_emb; xa.wbf[2] = wbfS0;  xa.dst[2] = Ys; xa.n[2] = U_N;
        xa.base[0] = 0; xa.base[1] = xb_i; xa.base[2] = xb_i + xb_u; xa.base[3] = xb_i + 2 * xb_u;
        xform_mfma<<<xa.base[3], nthr, 0, stream>>>(xa);
    }

    // 8) spmm L0: user<-Yi, item<-Yu, soc user<-Ys
    {
        SpArgs pa;
        pa.rptr[0] = rp_ui;  pa.pairs[0] = pairs_ui;  pa.y[0] = Yi; pa.cur[0] = user_emb;
        pa.bias[0] = ui_b;  pa.gamma[0] = ln_ui_g;  pa.beta[0] = ln_ui_b;  pa.dst[0] = o_ui1;
        pa.rptr[1] = rp_uiT; pa.pairs[1] = pairs_uiT; pa.y[1] = Yu; pa.cur[1] = item_emb;
        pa.bias[1] = ui_b;  pa.gamma[1] = ln_ui_g;  pa.beta[1] = ln_ui_b;  pa.dst[1] = o_ci;
        pa.rptr[2] = rp_soc; pa.pairs[2] = pairs_soc; pa.y[2] = Ys; pa.cur[2] = user_emb;
        pa.bias[2] = soc_b; pa.gamma[2] = ln_soc_g; pa.beta[2] = ln_soc_b; pa.dst[2] = o_s1;
        pa.base[0] = 0; pa.base[1] = U_N / 16; pa.base[2] = U_N / 16 + I_N / 16;
        pa.base[3] = 2 * (U_N / 16) + I_N / 16;
        spmm_ln<<<pa.base[3], nthr, 0, stream>>>(pa);
    }

    // 9) T1: Yi=T(ci1,W1ui), Yu=T(cu1,W1ui), Ys=T(cs1,W1soc)
    {
        XfArgs xa;
        xa.src[0] = o_ci;  xa.wbf[0] = wbfUI1; xa.dst[0] = Yi; xa.n[0] = I_N;
        xa.src[1] = o_ui1; xa.wbf[1] = wbfUI1; xa.dst[1] = Yu; xa.n[1] = U_N;
        xa.src[2] = o_s1;  xa.wbf[2] = wbfS1;  xa.dst[2] = Ys; xa.n[2] = U_N;
        xa.base[0] = 0; xa.base[1] = xb_i; xa.base[2] = xb_i + xb_u; xa.base[3] = xb_i + 2 * xb_u;
        xform_mfma<<<xa.base[3], nthr, 0, stream>>>(xa);
    }

    // 10) spmm L1
    {
        SpArgs pa;
        pa.rptr[0] = rp_ui;  pa.pairs[0] = pairs_ui;  pa.y[0] = Yi; pa.cur[0] = o_ui1;
        pa.bias[0] = ui_b + 64;  pa.gamma[0] = ln_ui_g + 64;  pa.beta[0] = ln_ui_b + 64;
        pa.dst[0] = o_ui2;
        pa.rptr[1] = rp_uiT; pa.pairs[1] = pairs_uiT; pa.y[1] = Yu; pa.cur[1] = o_ci;
        pa.bias[1] = ui_b + 64;  pa.gamma[1] = ln_ui_g + 64;  pa.beta[1] = ln_ui_b + 64;
        pa.dst[1] = o_ci;   // in-place: each row read then written by same thread
        pa.rptr[2] = rp_soc; pa.pairs[2] = pairs_soc; pa.y[2] = Ys; pa.cur[2] = o_s1;
        pa.bias[2] = soc_b + 64; pa.gamma[2] = ln_soc_g + 64; pa.beta[2] = ln_soc_b + 64;
        pa.dst[2] = o_s2;
        pa.base[0] = 0; pa.base[1] = U_N / 16; pa.base[2] = U_N / 16 + I_N / 16;
        pa.base[3] = 2 * (U_N / 16) + I_N / 16;
        spmm_ln<<<pa.base[3], nthr, 0, stream>>>(pa);
    }
}

// Round 5
// 821.042 us; speedup vs baseline: 10.7549x; 1.0415x over previous
//
#include <hip/hip_runtime.h>

#define U_N 100000
#define I_N 200000
#define D   64
#define NNZ_UI 2000000
#define NNZ_SOC 1000000
#define LN_EPS 1e-5f
#define LSLOPE 0.01f
#define SCAN_CHUNK 1024
#define SEDGES 2048   // edges staged in LDS per scatter block

using short8 = __attribute__((ext_vector_type(8))) short;
using f32x4  = __attribute__((ext_vector_type(4))) float;

__device__ __forceinline__ float bf2f(unsigned short h) {
    return __uint_as_float((unsigned int)h << 16);
}
__device__ __forceinline__ unsigned short f2bf(float f) {   // RNE
    unsigned int u = __float_as_uint(f);
    return (unsigned short)((u + 0x7FFFu + ((u >> 16) & 1u)) >> 16);
}

// ---------------------------------------------------------------------------
__global__ void zero_i4(int4* __restrict__ p, int n4) {
    int i = blockIdx.x * blockDim.x + threadIdx.x;
    if (i < n4) p[i] = make_int4(0, 0, 0, 0);
}

__global__ void copy2_f4(const float4* __restrict__ src, float4* __restrict__ d1,
                         float4* __restrict__ d2, int n4) {
    int i = blockIdx.x * blockDim.x + threadIdx.x;
    if (i < n4) {
        float4 v = src[i];
        d1[i] = v;
        d2[i] = v;
    }
}

// convert ui_W (8192 f32) then soc_W (8192 f32) into contiguous bf16
__global__ void wbf_k(const float* __restrict__ wa, const float* __restrict__ wb,
                      unsigned short* __restrict__ dst) {
    int i = blockIdx.x * blockDim.x + threadIdx.x;
    float v = (i < 8192) ? wa[i] : wb[i - 8192];
    dst[i] = f2bf(v);
}

// ---------------------------------------------------------------------------
// merged histogram (int4 reads)
struct HistArgs {
    const int4* rows4[3];
    int* cnt[3];
    int n4[3];
    int base[4];
};
__global__ __launch_bounds__(256) void hist_m(HistArgs a) {
    int b = blockIdx.x;
    int si = (b >= a.base[1]) + (b >= a.base[2]);
    int i = (b - a.base[si]) * 256 + threadIdx.x;
    if (i < a.n4[si]) {
        int4 v = a.rows4[si][i];
        int* c = a.cnt[si];
        atomicAdd(&c[v.x], 1);
        atomicAdd(&c[v.y], 1);
        atomicAdd(&c[v.z], 1);
        atomicAdd(&c[v.w], 1);
    }
}

// merged scans -------------------------------------------------------------
struct ScanArgs {
    int* cnt[3];
    int n[3];
    int off[3];
    int nb[3];
    int base[4];
};

__global__ __launch_bounds__(256) void scan_p1(ScanArgs a, int* __restrict__ bsum) {
    int b = blockIdx.x;
    int si = (b >= a.base[1]) + (b >= a.base[2]);
    int lb = b - a.base[si];
    const int* cnt = a.cnt[si];
    int n = a.n[si];
    int bs = lb * SCAN_CHUNK + threadIdx.x * 4;
    int s = 0;
    #pragma unroll
    for (int q = 0; q < 4; ++q) {
        int idx = bs + q;
        if (idx < n) s += cnt[idx];
    }
    #pragma unroll
    for (int m = 1; m < 64; m <<= 1) s += __shfl_xor(s, m, 64);
    __shared__ int ws[4];
    if ((threadIdx.x & 63) == 0) ws[threadIdx.x >> 6] = s;
    __syncthreads();
    if (threadIdx.x == 0) bsum[a.off[si] + lb] = ws[0] + ws[1] + ws[2] + ws[3];
}

__global__ __launch_bounds__(256) void scan_p2(ScanArgs a, int* __restrict__ bsum) {
    int si = blockIdx.x;
    int nb = a.nb[si];
    int* bp = bsum + a.off[si];
    int t = threadIdx.x;
    int v = (t < nb) ? bp[t] : 0;
    int lane = t & 63, w = t >> 6;
    int x = v;
    #pragma unroll
    for (int m = 1; m < 64; m <<= 1) {
        int y = __shfl_up(x, m, 64);
        if (lane >= m) x += y;
    }
    __shared__ int wtot[4];
    if (lane == 63) wtot[w] = x;
    __syncthreads();
    int off = 0;
    for (int i = 0; i < w; ++i) off += wtot[i];
    if (t < nb) bp[t] = (x + off) - v;
}

__global__ __launch_bounds__(256) void scan_p3(ScanArgs a, const int* __restrict__ bsum) {
    int b = blockIdx.x;
    int si = (b >= a.base[1]) + (b >= a.base[2]);
    int lb = b - a.base[si];
    int* cnt = a.cnt[si];
    int n = a.n[si];
    int bs = lb * SCAN_CHUNK + threadIdx.x * 4;
    int v[4];
    int s = 0;
    #pragma unroll
    for (int q = 0; q < 4; ++q) {
        int idx = bs + q;
        v[q] = (idx < n) ? cnt[idx] : 0;
        s += v[q];
    }
    int lane = threadIdx.x & 63, w = threadIdx.x >> 6;
    int x = s;
    #pragma unroll
    for (int m = 1; m < 64; m <<= 1) {
        int y = __shfl_up(x, m, 64);
        if (lane >= m) x += y;
    }
    __shared__ int wtot[4];
    if (lane == 63) wtot[w] = x;
    __syncthreads();
    int off = 0;
    for (int i = 0; i < w; ++i) off += wtot[i];
    int run = bsum[a.off[si] + lb] + (x - s) + off;
    #pragma unroll
    for (int q = 0; q < 4; ++q) {
        int idx = bs + q;
        int t = v[q];
        if (idx < n) cnt[idx] = run;
        run += t;
    }
}

// ---------------------------------------------------------------------------
// LDS-staged partitioned scatter: block stages its 2048-edge chunk in LDS once,
// then sweeps row-partitions writing matched edges. No global re-reads; writes
// cluster in ~1MB windows so L2 lines fill before eviction.
__global__ __launch_bounds__(256) void scatter_lds(
    const int* __restrict__ rows, const int* __restrict__ cols,
    const float* __restrict__ vals, int* __restrict__ rptr,
    int2* __restrict__ pairs, int nnz, int span, int nparts)
{
    __shared__ int   lr[SEDGES];
    __shared__ int   lc[SEDGES];
    __shared__ float lv[SEDGES];
    const int base = blockIdx.x * SEDGES;
    const int cnt  = min(SEDGES, nnz - base);
    for (int i = threadIdx.x; i < cnt; i += 256) {
        lr[i] = rows[base + i];
        lc[i] = cols[base + i];
        lv[i] = vals[base + i];
    }
    __syncthreads();
    int lo = 0;
    for (int p = 0; p < nparts; ++p, lo += span) {
        for (int k = threadIdx.x; k < cnt; k += 256) {
            int r = lr[k];
            if ((unsigned)(r - lo) < (unsigned)span) {
                int pos = atomicAdd(&rptr[r], 1);
                pairs[pos] = make_int2(lc[k], __float_as_int(lv[k]));
            }
        }
    }
}

// ---------------------------------------------------------------------------
// MFMA transform: dst_bf16[n,64] = src_f32[n,64] @ W^T  (W given as bf16 rows)
struct XfArgs {
    const float* src[3];
    const unsigned short* wbf[3];
    unsigned short* dst[3];
    int n[3];
    int base[4];
};
__global__ __launch_bounds__(256) void xform_mfma(XfArgs a) {
    int b = blockIdx.x;
    int si = (b >= a.base[1]) + (b >= a.base[2]);
    const float* src = a.src[si];
    const unsigned short* wb = a.wbf[si];
    unsigned short* dst = a.dst[si];
    const int n = a.n[si];

    const int lane = threadIdx.x & 63;
    const int wv   = threadIdx.x >> 6;
    const int rbw  = (b - a.base[si]) * 64 + wv * 16;
    const int m = lane & 15, g = lane >> 4;

    f32x4 acc0 = {0.f, 0.f, 0.f, 0.f};
    f32x4 acc1 = acc0, acc2 = acc0, acc3 = acc0;

    const int arow = min(rbw + m, n - 1);
    const float* xp = src + (size_t)arow * D + g * 8;
    const unsigned short* wp0 = wb + (size_t)m * D + g * 8;

    #pragma unroll
    for (int t = 0; t < 2; ++t) {
        float4 a0 = *(const float4*)(xp + t * 32);
        float4 a1 = *(const float4*)(xp + t * 32 + 4);
        short8 af;
        af[0] = (short)f2bf(a0.x); af[1] = (short)f2bf(a0.y);
        af[2] = (short)f2bf(a0.z); af[3] = (short)f2bf(a0.w);
        af[4] = (short)f2bf(a1.x); af[5] = (short)f2bf(a1.y);
        af[6] = (short)f2bf(a1.z); af[7] = (short)f2bf(a1.w);
        const unsigned short* wp = wp0 + t * 32;
        short8 b0 = *(const short8*)(wp);
        short8 b1 = *(const short8*)(wp + 16 * D);
        short8 b2 = *(const short8*)(wp + 32 * D);
        short8 b3 = *(const short8*)(wp + 48 * D);
        acc0 = __builtin_amdgcn_mfma_f32_16x16x32_bf16(af, b0, acc0, 0, 0, 0);
        acc1 = __builtin_amdgcn_mfma_f32_16x16x32_bf16(af, b1, acc1, 0, 0, 0);
        acc2 = __builtin_amdgcn_mfma_f32_16x16x32_bf16(af, b2, acc2, 0, 0, 0);
        acc3 = __builtin_amdgcn_mfma_f32_16x16x32_bf16(af, b3, acc3, 0, 0, 0);
    }

    #pragma unroll
    for (int reg = 0; reg < 4; ++reg) {
        int orow = rbw + g * 4 + reg;
        if (orow < n) {
            size_t o = (size_t)orow * D + m;
            dst[o]      = f2bf(acc0[reg]);
            dst[o + 16] = f2bf(acc1[reg]);
            dst[o + 32] = f2bf(acc2[reg]);
            dst[o + 48] = f2bf(acc3[reg]);
        }
    }
}

// ---------------------------------------------------------------------------
// Light SpMM + epilogue: agg = sum val*Y[col]; h = leaky(agg + b);
// y = LN(cur + h)*g + be.  16 lanes/row, 4 rows/wave, 16 rows/block.
struct SpArgs {
    const int* rptr[3];
    const int2* pairs[3];
    const unsigned short* y[3];
    const float* cur[3];
    const float* bias[3];
    const float* gamma[3];
    const float* beta[3];
    float* dst[3];
    int base[4];
};
__global__ __launch_bounds__(256) void spmm_ln(SpArgs a) {
    int b = blockIdx.x;
    int si = (b >= a.base[1]) + (b >= a.base[2]);
    const int* rptr = a.rptr[si];
    const int2* pairs = a.pairs[si];
    const unsigned short* y = a.y[si];

    const int lane = threadIdx.x & 63;
    const int wv   = threadIdx.x >> 6;
    const int r = lane >> 4, sub = lane & 15;
    const int row = (b - a.base[si]) * 16 + wv * 4 + r;

    const int start = (row == 0) ? 0 : rptr[row - 1];
    const int end   = rptr[row];

    float4 acc  = make_float4(0.f, 0.f, 0.f, 0.f);
    float4 acc2 = make_float4(0.f, 0.f, 0.f, 0.f);
    int e = start;
    for (; e + 4 <= end; e += 4) {
        int2 p0 = pairs[e];
        int2 p1 = pairs[e + 1];
        int2 p2 = pairs[e + 2];
        int2 p3 = pairs[e + 3];
        float v0 = __int_as_float(p0.y);
        float v1 = __int_as_float(p1.y);
        float v2 = __int_as_float(p2.y);
        float v3 = __int_as_float(p3.y);
        ushort4 q0 = *(const ushort4*)(y + (size_t)p0.x * D + sub * 4);
        ushort4 q1 = *(const ushort4*)(y + (size_t)p1.x * D + sub * 4);
        ushort4 q2 = *(const ushort4*)(y + (size_t)p2.x * D + sub * 4);
        ushort4 q3 = *(const ushort4*)(y + (size_t)p3.x * D + sub * 4);
        acc.x  += v0 * bf2f(q0.x); acc.y  += v0 * bf2f(q0.y);
        acc.z  += v0 * bf2f(q0.z); acc.w  += v0 * bf2f(q0.w);
        acc2.x += v1 * bf2f(q1.x); acc2.y += v1 * bf2f(q1.y);
        acc2.z += v1 * bf2f(q1.z); acc2.w += v1 * bf2f(q1.w);
        acc.x  += v2 * bf2f(q2.x); acc.y  += v2 * bf2f(q2.y);
        acc.z  += v2 * bf2f(q2.z); acc.w  += v2 * bf2f(q2.w);
        acc2.x += v3 * bf2f(q3.x); acc2.y += v3 * bf2f(q3.y);
        acc2.z += v3 * bf2f(q3.z); acc2.w += v3 * bf2f(q3.w);
    }
    for (; e < end; ++e) {
        int2 p0 = pairs[e];
        float v0 = __int_as_float(p0.y);
        ushort4 q0 = *(const ushort4*)(y + (size_t)p0.x * D + sub * 4);
        acc.x += v0 * bf2f(q0.x); acc.y += v0 * bf2f(q0.y);
        acc.z += v0 * bf2f(q0.z); acc.w += v0 * bf2f(q0.w);
    }
    acc.x += acc2.x; acc.y += acc2.y; acc.z += acc2.z; acc.w += acc2.w;

    float4 bi = *(const float4*)(a.bias[si] + sub * 4);
    float4 h;
    h.x = acc.x + bi.x; h.y = acc.y + bi.y; h.z = acc.z + bi.z; h.w = acc.w + bi.w;
    h.x = h.x > 0.f ? h.x : LSLOPE * h.x;
    h.y = h.y > 0.f ? h.y : LSLOPE * h.y;
    h.z = h.z > 0.f ? h.z : LSLOPE * h.z;
    h.w = h.w > 0.f ? h.w : LSLOPE * h.w;
    float4 cu = *(const float4*)(a.cur[si] + (size_t)row * D + sub * 4);
    float4 x;
    x.x = cu.x + h.x; x.y = cu.y + h.y; x.z = cu.z + h.z; x.w = cu.w + h.w;

    float s  = x.x + x.y + x.z + x.w;
    float s2 = x.x * x.x + x.y * x.y + x.z * x.z + x.w * x.w;
    #pragma unroll
    for (int m = 8; m >= 1; m >>= 1) {
        s  += __shfl_xor(s, m, 64);
        s2 += __shfl_xor(s2, m, 64);
    }
    float mean = s * (1.f / 64.f);
    float var  = s2 * (1.f / 64.f) - mean * mean;
    float rstd = rsqrtf(var + LN_EPS);

    float4 g4  = *(const float4*)(a.gamma[si] + sub * 4);
    float4 be4 = *(const float4*)(a.beta[si]  + sub * 4);
    float4 o;
    o.x = (x.x - mean) * rstd * g4.x + be4.x;
    o.y = (x.y - mean) * rstd * g4.y + be4.y;
    o.z = (x.z - mean) * rstd * g4.z + be4.z;
    o.w = (x.w - mean) * rstd * g4.w + be4.w;
    *(float4*)(a.dst[si] + (size_t)row * D + sub * 4) = o;
}

// ---------------------------------------------------------------------------
extern "C" void kernel_launch(void* const* d_in, const int* in_sizes, int n_in,
                              void* d_out, int out_size, void* d_ws, size_t ws_size,
                              hipStream_t stream)
{
    const float* user_emb = (const float*)d_in[0];
    const float* item_emb = (const float*)d_in[1];
    const int*   ui_rows  = (const int*)d_in[2];
    const int*   ui_cols  = (const int*)d_in[3];
    const float* ui_vals  = (const float*)d_in[4];
    const int*   soc_rows = (const int*)d_in[5];
    const int*   soc_cols = (const int*)d_in[6];
    const float* soc_vals = (const float*)d_in[7];
    const float* ui_W     = (const float*)d_in[8];
    const float* ui_b     = (const float*)d_in[9];
    const float* soc_W    = (const float*)d_in[10];
    const float* soc_b    = (const float*)d_in[11];
    const float* ln_ui_g  = (const float*)d_in[12];
    const float* ln_ui_b  = (const float*)d_in[13];
    const float* ln_soc_g = (const float*)d_in[14];
    const float* ln_soc_b = (const float*)d_in[15];

    float* out = (float*)d_out;
    const size_t UD = (size_t)U_N * D;
    const size_t ID = (size_t)I_N * D;

    float* o_ui0 = out;
    float* o_ui1 = out + UD;
    float* o_ui2 = out + 2 * UD;
    float* o_s0  = out + 3 * UD;
    float* o_s1  = out + 4 * UD;
    float* o_s2  = out + 5 * UD;
    float* o_ci  = out + 6 * UD;

    // workspace layout
    int2* pairs_ui  = (int2*)d_ws;                       // 16 MB
    int2* pairs_uiT = pairs_ui + NNZ_UI;                 // 16 MB
    int2* pairs_soc = pairs_uiT + NNZ_UI;                // 8 MB
    int*  rp_ui     = (int*)(pairs_soc + NNZ_SOC);       // U
    int*  rp_uiT    = rp_ui + U_N;                       // I
    int*  rp_soc    = rp_uiT + I_N;                      // U
    int*  bsum      = rp_soc + U_N;                      // 512
    unsigned short* wbf = (unsigned short*)(bsum + 512); // 4 x 4096 bf16
    unsigned short* Yi  = wbf + 4 * 4096;                // I*D bf16
    unsigned short* Yu  = Yi + ID;                       // U*D bf16
    unsigned short* Ys  = Yu + UD;                       // U*D bf16

    const unsigned short* wbfUI0 = wbf;
    const unsigned short* wbfUI1 = wbf + 4096;
    const unsigned short* wbfS0  = wbf + 8192;
    const unsigned short* wbfS1  = wbf + 12288;

    const int nthr = 256;

    // 1) zero count arrays
    {
        int ntot = U_N + I_N + U_N;
        zero_i4<<<(ntot / 4 + nthr - 1) / nthr, nthr, 0, stream>>>((int4*)rp_ui, ntot / 4);
    }

    // 2) weights to bf16
    wbf_k<<<64, nthr, 0, stream>>>(ui_W, soc_W, wbf);

    // 3) merged histogram
    {
        HistArgs ha;
        ha.rows4[0] = (const int4*)ui_rows;  ha.cnt[0] = rp_ui;  ha.n4[0] = NNZ_UI / 4;
        ha.rows4[1] = (const int4*)ui_cols;  ha.cnt[1] = rp_uiT; ha.n4[1] = NNZ_UI / 4;
        ha.rows4[2] = (const int4*)soc_rows; ha.cnt[2] = rp_soc; ha.n4[2] = NNZ_SOC / 4;
        int g0 = (ha.n4[0] + nthr - 1) / nthr, g1 = (ha.n4[1] + nthr - 1) / nthr,
            g2 = (ha.n4[2] + nthr - 1) / nthr;
        ha.base[0] = 0; ha.base[1] = g0; ha.base[2] = g0 + g1; ha.base[3] = g0 + g1 + g2;
        hist_m<<<ha.base[3], nthr, 0, stream>>>(ha);
    }

    // 4) merged scans
    {
        ScanArgs sa;
        sa.cnt[0] = rp_ui;  sa.n[0] = U_N;
        sa.cnt[1] = rp_uiT; sa.n[1] = I_N;
        sa.cnt[2] = rp_soc; sa.n[2] = U_N;
        int nb0 = (U_N + SCAN_CHUNK - 1) / SCAN_CHUNK;
        int nb1 = (I_N + SCAN_CHUNK - 1) / SCAN_CHUNK;
        int nb2 = nb0;
        sa.nb[0] = nb0; sa.nb[1] = nb1; sa.nb[2] = nb2;
        sa.off[0] = 0; sa.off[1] = nb0; sa.off[2] = nb0 + nb1;
        sa.base[0] = 0; sa.base[1] = nb0; sa.base[2] = nb0 + nb1; sa.base[3] = nb0 + nb1 + nb2;
        scan_p1<<<sa.base[3], nthr, 0, stream>>>(sa, bsum);
        scan_p2<<<3, nthr, 0, stream>>>(sa, bsum);
        scan_p3<<<sa.base[3], nthr, 0, stream>>>(sa, bsum);
    }

    // 5) LDS-staged partitioned scatters (3 separate dispatches)
    {
        int gb_ui  = (NNZ_UI  + SEDGES - 1) / SEDGES;   // 977
        int gb_soc = (NNZ_SOC + SEDGES - 1) / SEDGES;   // 489
        scatter_lds<<<gb_ui, nthr, 0, stream>>>(ui_rows, ui_cols, ui_vals,
                                                rp_ui, pairs_ui, NNZ_UI, (U_N + 15) / 16, 16);
        scatter_lds<<<gb_ui, nthr, 0, stream>>>(ui_cols, ui_rows, ui_vals,
                                                rp_uiT, pairs_uiT, NNZ_UI, (I_N + 15) / 16, 16);
        scatter_lds<<<gb_soc, nthr, 0, stream>>>(soc_rows, soc_cols, soc_vals,
                                                 rp_soc, pairs_soc, NNZ_SOC, (U_N + 7) / 8, 8);
    }

    // 6) copy user_emb to output slots
    copy2_f4<<<(int)(UD / 4 + nthr - 1) / nthr, nthr, 0, stream>>>(
        (const float4*)user_emb, (float4*)o_ui0, (float4*)o_s0, (int)(UD / 4));

    const int xb_i = (I_N + 63) / 64;
    const int xb_u = (U_N + 63) / 64;

    // 7) T0
    {
        XfArgs xa;
        xa.src[0] = item_emb; xa.wbf[0] = wbfUI0; xa.dst[0] = Yi; xa.n[0] = I_N;
        xa.src[1] = user_emb; xa.wbf[1] = wbfUI0; xa.dst[1] = Yu; xa.n[1] = U_N;
        xa.src[2] = user_emb; xa.wbf[2] = wbfS0;  xa.dst[2] = Ys; xa.n[2] = U_N;
        xa.base[0] = 0; xa.base[1] = xb_i; xa.base[2] = xb_i + xb_u; xa.base[3] = xb_i + 2 * xb_u;
        xform_mfma<<<xa.base[3], nthr, 0, stream>>>(xa);
    }

    // 8) spmm L0
    {
        SpArgs pa;
        pa.rptr[0] = rp_ui;  pa.pairs[0] = pairs_ui;  pa.y[0] = Yi; pa.cur[0] = user_emb;
        pa.bias[0] = ui_b;  pa.gamma[0] = ln_ui_g;  pa.beta[0] = ln_ui_b;  pa.dst[0] = o_ui1;
        pa.rptr[1] = rp_uiT; pa.pairs[1] = pairs_uiT; pa.y[1] = Yu; pa.cur[1] = item_emb;
        pa.bias[1] = ui_b;  pa.gamma[1] = ln_ui_g;  pa.beta[1] = ln_ui_b;  pa.dst[1] = o_ci;
        pa.rptr[2] = rp_soc; pa.pairs[2] = pairs_soc; pa.y[2] = Ys; pa.cur[2] = user_emb;
        pa.bias[2] = soc_b; pa.gamma[2] = ln_soc_g; pa.beta[2] = ln_soc_b; pa.dst[2] = o_s1;
        pa.base[0] = 0; pa.base[1] = U_N / 16; pa.base[2] = U_N / 16 + I_N / 16;
        pa.base[3] = 2 * (U_N / 16) + I_N / 16;
        spmm_ln<<<pa.base[3], nthr, 0, stream>>>(pa);
    }

    // 9) T1
    {
        XfArgs xa;
        xa.src[0] = o_ci;  xa.wbf[0] = wbfUI1; xa.dst[0] = Yi; xa.n[0] = I_N;
        xa.src[1] = o_ui1; xa.wbf[1] = wbfUI1; xa.dst[1] = Yu; xa.n[1] = U_N;
        xa.src[2] = o_s1;  xa.wbf[2] = wbfS1;  xa.dst[2] = Ys; xa.n[2] = U_N;
        xa.base[0] = 0; xa.base[1] = xb_i; xa.base[2] = xb_i + xb_u; xa.base[3] = xb_i + 2 * xb_u;
        xform_mfma<<<xa.base[3], nthr, 0, stream>>>(xa);
    }

    // 10) spmm L1
    {
        SpArgs pa;
        pa.rptr[0] = rp_ui;  pa.pairs[0] = pairs_ui;  pa.y[0] = Yi; pa.cur[0] = o_ui1;
        pa.bias[0] = ui_b + 64;  pa.gamma[0] = ln_ui_g + 64;  pa.beta[0] = ln_ui_b + 64;
        pa.dst[0] = o_ui2;
        pa.rptr[1] = rp_uiT; pa.pairs[1] = pairs_uiT; pa.y[1] = Yu; pa.cur[1] = o_ci;
        pa.bias[1] = ui_b + 64;  pa.gamma[1] = ln_ui_g + 64;  pa.beta[1] = ln_ui_b + 64;
        pa.dst[1] = o_ci;   // in-place: each row read then written by same thread
        pa.rptr[2] = rp_soc; pa.pairs[2] = pairs_soc; pa.y[2] = Ys; pa.cur[2] = o_s1;
        pa.bias[2] = soc_b + 64; pa.gamma[2] = ln_soc_g + 64; pa.beta[2] = ln_soc_b + 64;
        pa.dst[2] = o_s2;
        pa.base[0] = 0; pa.base[1] = U_N / 16; pa.base[2] = U_N / 16 + I_N / 16;
        pa.base[3] = 2 * (U_N / 16) + I_N / 16;
        spmm_ln<<<pa.base[3], nthr, 0, stream>>>(pa);
    }
}

// Round 7
// 803.143 us; speedup vs baseline: 10.9945x; 1.0223x over previous
//
#include <hip/hip_runtime.h>

#define U_N 100000
#define I_N 200000
#define D   64
#define NNZ_UI 2000000
#define NNZ_SOC 1000000
#define LN_EPS 1e-5f
#define LSLOPE 0.01f
#define SCAN_CHUNK 1024
#define SEDGES 2048   // edges per hist/scatter block (MUST match between them)
#define NREP 8        // counter replicas (contention reduction)

using short8 = __attribute__((ext_vector_type(8))) short;
using f32x4  = __attribute__((ext_vector_type(4))) float;

__device__ __forceinline__ float bf2f(unsigned short h) {
    return __uint_as_float((unsigned int)h << 16);
}
__device__ __forceinline__ unsigned short f2bf(float f) {   // RNE
    unsigned int u = __float_as_uint(f);
    return (unsigned short)((u + 0x7FFFu + ((u >> 16) & 1u)) >> 16);
}

// ---------------------------------------------------------------------------
__global__ void zero_i4(int4* __restrict__ p, int n4) {
    int i = blockIdx.x * blockDim.x + threadIdx.x;
    if (i < n4) p[i] = make_int4(0, 0, 0, 0);
}

__global__ void copy2_f4(const float4* __restrict__ src, float4* __restrict__ d1,
                         float4* __restrict__ d2, int n4) {
    int i = blockIdx.x * blockDim.x + threadIdx.x;
    if (i < n4) {
        float4 v = src[i];
        d1[i] = v;
        d2[i] = v;
    }
}

__global__ void wbf_k(const float* __restrict__ wa, const float* __restrict__ wb,
                      unsigned short* __restrict__ dst) {
    int i = blockIdx.x * blockDim.x + threadIdx.x;
    float v = (i < 8192) ? wa[i] : wb[i - 8192];
    dst[i] = f2bf(v);
}

// ---------------------------------------------------------------------------
// replicated histogram. Each block covers exactly SEDGES=2048 edges (512 int4,
// 2 per thread) and uses replica (local_block & 7) — the SAME map as the
// scatter, so per-(replica,row) segment sizes match their usage exactly.
struct HistArgs {
    const int4* rows4[3];
    int* cg[3];
    int n4[3];
    int nrows[3];
    int base[4];
};
__global__ __launch_bounds__(256) void hist_m(HistArgs a) {
    int b = blockIdx.x;
    int si = (b >= a.base[1]) + (b >= a.base[2]);
    int lb = b - a.base[si];
    int* c = a.cg[si] + (lb & (NREP - 1)) * a.nrows[si];
    int i0 = lb * 512 + threadIdx.x;
    #pragma unroll
    for (int q = 0; q < 2; ++q) {
        int i = i0 + q * 256;
        if (i < a.n4[si]) {
            int4 v = a.rows4[si][i];
            atomicAdd(&c[v.x], 1);
            atomicAdd(&c[v.y], 1);
            atomicAdd(&c[v.z], 1);
            atomicAdd(&c[v.w], 1);
        }
    }
}

// merge: per row, replica counts -> row-local exclusive prefix; rp[r] = total
struct MrgArgs {
    int* cg[3];
    int* rp[3];
    int n[3];
    int base[4];
};
__global__ __launch_bounds__(256) void merge_k(MrgArgs a) {
    int b = blockIdx.x;
    int si = (b >= a.base[1]) + (b >= a.base[2]);
    int r = (b - a.base[si]) * 256 + threadIdx.x;
    int n = a.n[si];
    if (r >= n) return;
    int* cg = a.cg[si];
    int s = 0;
    #pragma unroll
    for (int g = 0; g < NREP; ++g) {
        int t = cg[g * n + r];
        cg[g * n + r] = s;
        s += t;
    }
    a.rp[si][r] = s;
}

// addback: cg[g][r] += rp[r] (row start) -> absolute segment starts
__global__ __launch_bounds__(256) void addback_k(MrgArgs a) {
    int b = blockIdx.x;
    int si = (b >= a.base[1]) + (b >= a.base[2]);
    int r = (b - a.base[si]) * 256 + threadIdx.x;
    int n = a.n[si];
    if (r >= n) return;
    int* cg = a.cg[si];
    int base = a.rp[si][r];
    #pragma unroll
    for (int g = 0; g < NREP; ++g) cg[g * n + r] += base;
}

// merged scans (over rp arrays; exclusive prefix -> row starts) --------------
struct ScanArgs {
    int* cnt[3];
    int n[3];
    int off[3];
    int nb[3];
    int base[4];
};

__global__ __launch_bounds__(256) void scan_p1(ScanArgs a, int* __restrict__ bsum) {
    int b = blockIdx.x;
    int si = (b >= a.base[1]) + (b >= a.base[2]);
    int lb = b - a.base[si];
    const int* cnt = a.cnt[si];
    int n = a.n[si];
    int bs = lb * SCAN_CHUNK + threadIdx.x * 4;
    int s = 0;
    #pragma unroll
    for (int q = 0; q < 4; ++q) {
        int idx = bs + q;
        if (idx < n) s += cnt[idx];
    }
    #pragma unroll
    for (int m = 1; m < 64; m <<= 1) s += __shfl_xor(s, m, 64);
    __shared__ int ws[4];
    if ((threadIdx.x & 63) == 0) ws[threadIdx.x >> 6] = s;
    __syncthreads();
    if (threadIdx.x == 0) bsum[a.off[si] + lb] = ws[0] + ws[1] + ws[2] + ws[3];
}

__global__ __launch_bounds__(256) void scan_p2(ScanArgs a, int* __restrict__ bsum) {
    int si = blockIdx.x;
    int nb = a.nb[si];
    int* bp = bsum + a.off[si];
    int t = threadIdx.x;
    int v = (t < nb) ? bp[t] : 0;
    int lane = t & 63, w = t >> 6;
    int x = v;
    #pragma unroll
    for (int m = 1; m < 64; m <<= 1) {
        int y = __shfl_up(x, m, 64);
        if (lane >= m) x += y;
    }
    __shared__ int wtot[4];
    if (lane == 63) wtot[w] = x;
    __syncthreads();
    int off = 0;
    for (int i = 0; i < w; ++i) off += wtot[i];
    if (t < nb) bp[t] = (x + off) - v;
}

__global__ __launch_bounds__(256) void scan_p3(ScanArgs a, const int* __restrict__ bsum) {
    int b = blockIdx.x;
    int si = (b >= a.base[1]) + (b >= a.base[2]);
    int lb = b - a.base[si];
    int* cnt = a.cnt[si];
    int n = a.n[si];
    int bs = lb * SCAN_CHUNK + threadIdx.x * 4;
    int v[4];
    int s = 0;
    #pragma unroll
    for (int q = 0; q < 4; ++q) {
        int idx = bs + q;
        v[q] = (idx < n) ? cnt[idx] : 0;
        s += v[q];
    }
    int lane = threadIdx.x & 63, w = threadIdx.x >> 6;
    int x = s;
    #pragma unroll
    for (int m = 1; m < 64; m <<= 1) {
        int y = __shfl_up(x, m, 64);
        if (lane >= m) x += y;
    }
    __shared__ int wtot[4];
    if (lane == 63) wtot[w] = x;
    __syncthreads();
    int off = 0;
    for (int i = 0; i < w; ++i) off += wtot[i];
    int run = bsum[a.off[si] + lb] + (x - s) + off;
    #pragma unroll
    for (int q = 0; q < 4; ++q) {
        int idx = bs + q;
        int t = v[q];
        if (idx < n) cnt[idx] = run;
        run += t;
    }
}

// ---------------------------------------------------------------------------
// LDS-staged partitioned scatter; positions from this block's replica
// counters. Block lb covers edges [lb*SEDGES, (lb+1)*SEDGES) and uses
// replica (lb & 7) — identical to hist_m's mapping.
__global__ __launch_bounds__(256) void scatter_lds(
    const int* __restrict__ rows, const int* __restrict__ cols,
    const float* __restrict__ vals, int* __restrict__ cg, int nrows,
    int2* __restrict__ pairs, int nnz, int span, int nparts)
{
    __shared__ int   lr[SEDGES];
    __shared__ int   lc[SEDGES];
    __shared__ float lv[SEDGES];
    const int base = blockIdx.x * SEDGES;
    const int cnt  = min(SEDGES, nnz - base);
    int* ctr = cg + (blockIdx.x & (NREP - 1)) * nrows;
    for (int i = threadIdx.x; i < cnt; i += 256) {
        lr[i] = rows[base + i];
        lc[i] = cols[base + i];
        lv[i] = vals[base + i];
    }
    __syncthreads();
    int lo = 0;
    for (int p = 0; p < nparts; ++p, lo += span) {
        for (int k = threadIdx.x; k < cnt; k += 256) {
            int r = lr[k];
            if ((unsigned)(r - lo) < (unsigned)span) {
                int pos = atomicAdd(&ctr[r], 1);
                pairs[pos] = make_int2(lc[k], __float_as_int(lv[k]));
            }
        }
    }
}

// ---------------------------------------------------------------------------
// MFMA transform: dst_bf16[n,64] = src_f32[n,64] @ W^T
struct XfArgs {
    const float* src[3];
    const unsigned short* wbf[3];
    unsigned short* dst[3];
    int n[3];
    int base[4];
};
__global__ __launch_bounds__(256) void xform_mfma(XfArgs a) {
    int b = blockIdx.x;
    int si = (b >= a.base[1]) + (b >= a.base[2]);
    const float* src = a.src[si];
    const unsigned short* wb = a.wbf[si];
    unsigned short* dst = a.dst[si];
    const int n = a.n[si];

    const int lane = threadIdx.x & 63;
    const int wv   = threadIdx.x >> 6;
    const int rbw  = (b - a.base[si]) * 64 + wv * 16;
    const int m = lane & 15, g = lane >> 4;

    f32x4 acc0 = {0.f, 0.f, 0.f, 0.f};
    f32x4 acc1 = acc0, acc2 = acc0, acc3 = acc0;

    const int arow = min(rbw + m, n - 1);
    const float* xp = src + (size_t)arow * D + g * 8;
    const unsigned short* wp0 = wb + (size_t)m * D + g * 8;

    #pragma unroll
    for (int t = 0; t < 2; ++t) {
        float4 a0 = *(const float4*)(xp + t * 32);
        float4 a1 = *(const float4*)(xp + t * 32 + 4);
        short8 af;
        af[0] = (short)f2bf(a0.x); af[1] = (short)f2bf(a0.y);
        af[2] = (short)f2bf(a0.z); af[3] = (short)f2bf(a0.w);
        af[4] = (short)f2bf(a1.x); af[5] = (short)f2bf(a1.y);
        af[6] = (short)f2bf(a1.z); af[7] = (short)f2bf(a1.w);
        const unsigned short* wp = wp0 + t * 32;
        short8 b0 = *(const short8*)(wp);
        short8 b1 = *(const short8*)(wp + 16 * D);
        short8 b2 = *(const short8*)(wp + 32 * D);
        short8 b3 = *(const short8*)(wp + 48 * D);
        acc0 = __builtin_amdgcn_mfma_f32_16x16x32_bf16(af, b0, acc0, 0, 0, 0);
        acc1 = __builtin_amdgcn_mfma_f32_16x16x32_bf16(af, b1, acc1, 0, 0, 0);
        acc2 = __builtin_amdgcn_mfma_f32_16x16x32_bf16(af, b2, acc2, 0, 0, 0);
        acc3 = __builtin_amdgcn_mfma_f32_16x16x32_bf16(af, b3, acc3, 0, 0, 0);
    }

    #pragma unroll
    for (int reg = 0; reg < 4; ++reg) {
        int orow = rbw + g * 4 + reg;
        if (orow < n) {
            size_t o = (size_t)orow * D + m;
            dst[o]      = f2bf(acc0[reg]);
            dst[o + 16] = f2bf(acc1[reg]);
            dst[o + 32] = f2bf(acc2[reg]);
            dst[o + 48] = f2bf(acc3[reg]);
        }
    }
}

// ---------------------------------------------------------------------------
// Light SpMM + epilogue. rp holds row STARTS; end = (row==n-1)?nnz:rp[row+1].
struct SpArgs {
    const int* rptr[3];
    const int2* pairs[3];
    const unsigned short* y[3];
    const float* cur[3];
    const float* bias[3];
    const float* gamma[3];
    const float* beta[3];
    float* dst[3];
    int n[3];
    int nnzc[3];
    int base[4];
};
__global__ __launch_bounds__(256) void spmm_ln(SpArgs a) {
    int b = blockIdx.x;
    int si = (b >= a.base[1]) + (b >= a.base[2]);
    const int* rptr = a.rptr[si];
    const int2* pairs = a.pairs[si];
    const unsigned short* y = a.y[si];

    const int lane = threadIdx.x & 63;
    const int wv   = threadIdx.x >> 6;
    const int r = lane >> 4, sub = lane & 15;
    const int row = (b - a.base[si]) * 16 + wv * 4 + r;

    const int start = rptr[row];
    const int end   = (row == a.n[si] - 1) ? a.nnzc[si] : rptr[row + 1];

    float4 acc  = make_float4(0.f, 0.f, 0.f, 0.f);
    float4 acc2 = make_float4(0.f, 0.f, 0.f, 0.f);
    int e = start;
    for (; e + 4 <= end; e += 4) {
        int2 p0 = pairs[e];
        int2 p1 = pairs[e + 1];
        int2 p2 = pairs[e + 2];
        int2 p3 = pairs[e + 3];
        float v0 = __int_as_float(p0.y);
        float v1 = __int_as_float(p1.y);
        float v2 = __int_as_float(p2.y);
        float v3 = __int_as_float(p3.y);
        ushort4 q0 = *(const ushort4*)(y + (size_t)p0.x * D + sub * 4);
        ushort4 q1 = *(const ushort4*)(y + (size_t)p1.x * D + sub * 4);
        ushort4 q2 = *(const ushort4*)(y + (size_t)p2.x * D + sub * 4);
        ushort4 q3 = *(const ushort4*)(y + (size_t)p3.x * D + sub * 4);
        acc.x  += v0 * bf2f(q0.x); acc.y  += v0 * bf2f(q0.y);
        acc.z  += v0 * bf2f(q0.z); acc.w  += v0 * bf2f(q0.w);
        acc2.x += v1 * bf2f(q1.x); acc2.y += v1 * bf2f(q1.y);
        acc2.z += v1 * bf2f(q1.z); acc2.w += v1 * bf2f(q1.w);
        acc.x  += v2 * bf2f(q2.x); acc.y  += v2 * bf2f(q2.y);
        acc.z  += v2 * bf2f(q2.z); acc.w  += v2 * bf2f(q2.w);
        acc2.x += v3 * bf2f(q3.x); acc2.y += v3 * bf2f(q3.y);
        acc2.z += v3 * bf2f(q3.z); acc2.w += v3 * bf2f(q3.w);
    }
    for (; e < end; ++e) {
        int2 p0 = pairs[e];
        float v0 = __int_as_float(p0.y);
        ushort4 q0 = *(const ushort4*)(y + (size_t)p0.x * D + sub * 4);
        acc.x += v0 * bf2f(q0.x); acc.y += v0 * bf2f(q0.y);
        acc.z += v0 * bf2f(q0.z); acc.w += v0 * bf2f(q0.w);
    }
    acc.x += acc2.x; acc.y += acc2.y; acc.z += acc2.z; acc.w += acc2.w;

    float4 bi = *(const float4*)(a.bias[si] + sub * 4);
    float4 h;
    h.x = acc.x + bi.x; h.y = acc.y + bi.y; h.z = acc.z + bi.z; h.w = acc.w + bi.w;
    h.x = h.x > 0.f ? h.x : LSLOPE * h.x;
    h.y = h.y > 0.f ? h.y : LSLOPE * h.y;
    h.z = h.z > 0.f ? h.z : LSLOPE * h.z;
    h.w = h.w > 0.f ? h.w : LSLOPE * h.w;
    float4 cu = *(const float4*)(a.cur[si] + (size_t)row * D + sub * 4);
    float4 x;
    x.x = cu.x + h.x; x.y = cu.y + h.y; x.z = cu.z + h.z; x.w = cu.w + h.w;

    float s  = x.x + x.y + x.z + x.w;
    float s2 = x.x * x.x + x.y * x.y + x.z * x.z + x.w * x.w;
    #pragma unroll
    for (int m = 8; m >= 1; m >>= 1) {
        s  += __shfl_xor(s, m, 64);
        s2 += __shfl_xor(s2, m, 64);
    }
    float mean = s * (1.f / 64.f);
    float var  = s2 * (1.f / 64.f) - mean * mean;
    float rstd = rsqrtf(var + LN_EPS);

    float4 g4  = *(const float4*)(a.gamma[si] + sub * 4);
    float4 be4 = *(const float4*)(a.beta[si]  + sub * 4);
    float4 o;
    o.x = (x.x - mean) * rstd * g4.x + be4.x;
    o.y = (x.y - mean) * rstd * g4.y + be4.y;
    o.z = (x.z - mean) * rstd * g4.z + be4.z;
    o.w = (x.w - mean) * rstd * g4.w + be4.w;
    *(float4*)(a.dst[si] + (size_t)row * D + sub * 4) = o;
}

// ---------------------------------------------------------------------------
extern "C" void kernel_launch(void* const* d_in, const int* in_sizes, int n_in,
                              void* d_out, int out_size, void* d_ws, size_t ws_size,
                              hipStream_t stream)
{
    const float* user_emb = (const float*)d_in[0];
    const float* item_emb = (const float*)d_in[1];
    const int*   ui_rows  = (const int*)d_in[2];
    const int*   ui_cols  = (const int*)d_in[3];
    const float* ui_vals  = (const float*)d_in[4];
    const int*   soc_rows = (const int*)d_in[5];
    const int*   soc_cols = (const int*)d_in[6];
    const float* soc_vals = (const float*)d_in[7];
    const float* ui_W     = (const float*)d_in[8];
    const float* ui_b     = (const float*)d_in[9];
    const float* soc_W    = (const float*)d_in[10];
    const float* soc_b    = (const float*)d_in[11];
    const float* ln_ui_g  = (const float*)d_in[12];
    const float* ln_ui_b  = (const float*)d_in[13];
    const float* ln_soc_g = (const float*)d_in[14];
    const float* ln_soc_b = (const float*)d_in[15];

    float* out = (float*)d_out;
    const size_t UD = (size_t)U_N * D;
    const size_t ID = (size_t)I_N * D;

    float* o_ui0 = out;
    float* o_ui1 = out + UD;
    float* o_ui2 = out + 2 * UD;
    float* o_s0  = out + 3 * UD;
    float* o_s1  = out + 4 * UD;
    float* o_s2  = out + 5 * UD;
    float* o_ci  = out + 6 * UD;

    // workspace layout
    int2* pairs_ui  = (int2*)d_ws;                       // 2M
    int2* pairs_uiT = pairs_ui + NNZ_UI;                 // 2M
    int2* pairs_soc = pairs_uiT + NNZ_UI;                // 1M
    int*  rp_ui     = (int*)(pairs_soc + NNZ_SOC);       // U_N
    int*  rp_uiT    = rp_ui + U_N;                       // I_N
    int*  rp_soc    = rp_uiT + I_N;                      // U_N
    int*  bsum      = rp_soc + U_N;                      // 512
    unsigned short* wbf = (unsigned short*)(bsum + 512); // 16384
    unsigned short* Yi  = wbf + 16384;                   // I*D bf16
    unsigned short* Yu  = Yi + ID;                       // U*D bf16
    unsigned short* Ys  = Yu + UD;                       // U*D bf16
    // replica counters overlap Yi (12.8MB < 25.6MB); dead before T0 writes Yi
    int* cg_ui  = (int*)Yi;                              // NREP*U_N
    int* cg_uiT = cg_ui + NREP * U_N;                    // NREP*I_N
    int* cg_soc = cg_uiT + NREP * I_N;                   // NREP*U_N

    const unsigned short* wbfUI0 = wbf;
    const unsigned short* wbfUI1 = wbf + 4096;
    const unsigned short* wbfS0  = wbf + 8192;
    const unsigned short* wbfS1  = wbf + 12288;

    const int nthr = 256;

    // 1) zero replica counters (NREP * 400K ints, contiguous)
    {
        int ntot = NREP * (U_N + I_N + U_N);
        zero_i4<<<(ntot / 4 + nthr - 1) / nthr, nthr, 0, stream>>>((int4*)cg_ui, ntot / 4);
    }

    // 2) weights to bf16
    wbf_k<<<64, nthr, 0, stream>>>(ui_W, soc_W, wbf);

    // 3) replicated histogram (block = 2048 edges = scatter chunk)
    {
        HistArgs ha;
        ha.rows4[0] = (const int4*)ui_rows;  ha.cg[0] = cg_ui;  ha.n4[0] = NNZ_UI / 4;  ha.nrows[0] = U_N;
        ha.rows4[1] = (const int4*)ui_cols;  ha.cg[1] = cg_uiT; ha.n4[1] = NNZ_UI / 4;  ha.nrows[1] = I_N;
        ha.rows4[2] = (const int4*)soc_rows; ha.cg[2] = cg_soc; ha.n4[2] = NNZ_SOC / 4; ha.nrows[2] = U_N;
        int g0 = (NNZ_UI  + SEDGES - 1) / SEDGES;   // 977
        int g1 = g0;
        int g2 = (NNZ_SOC + SEDGES - 1) / SEDGES;   // 489
        ha.base[0] = 0; ha.base[1] = g0; ha.base[2] = g0 + g1; ha.base[3] = g0 + g1 + g2;
        hist_m<<<ha.base[3], nthr, 0, stream>>>(ha);
    }

    // 4) merge replicas -> local prefixes + totals, scan totals, add back
    MrgArgs ma;
    {
        ma.cg[0] = cg_ui;  ma.rp[0] = rp_ui;  ma.n[0] = U_N;
        ma.cg[1] = cg_uiT; ma.rp[1] = rp_uiT; ma.n[1] = I_N;
        ma.cg[2] = cg_soc; ma.rp[2] = rp_soc; ma.n[2] = U_N;
        int g0 = (U_N + nthr - 1) / nthr, g1 = (I_N + nthr - 1) / nthr, g2 = g0;
        ma.base[0] = 0; ma.base[1] = g0; ma.base[2] = g0 + g1; ma.base[3] = g0 + g1 + g2;
        merge_k<<<ma.base[3], nthr, 0, stream>>>(ma);
    }
    {
        ScanArgs sa;
        sa.cnt[0] = rp_ui;  sa.n[0] = U_N;
        sa.cnt[1] = rp_uiT; sa.n[1] = I_N;
        sa.cnt[2] = rp_soc; sa.n[2] = U_N;
        int nb0 = (U_N + SCAN_CHUNK - 1) / SCAN_CHUNK;
        int nb1 = (I_N + SCAN_CHUNK - 1) / SCAN_CHUNK;
        int nb2 = nb0;
        sa.nb[0] = nb0; sa.nb[1] = nb1; sa.nb[2] = nb2;
        sa.off[0] = 0; sa.off[1] = nb0; sa.off[2] = nb0 + nb1;
        sa.base[0] = 0; sa.base[1] = nb0; sa.base[2] = nb0 + nb1; sa.base[3] = nb0 + nb1 + nb2;
        scan_p1<<<sa.base[3], nthr, 0, stream>>>(sa, bsum);
        scan_p2<<<3, nthr, 0, stream>>>(sa, bsum);
        scan_p3<<<sa.base[3], nthr, 0, stream>>>(sa, bsum);
    }
    addback_k<<<ma.base[3], nthr, 0, stream>>>(ma);

    // 5) LDS-staged partitioned scatters (replica counters; 3 dispatches)
    {
        int gb_ui  = (NNZ_UI  + SEDGES - 1) / SEDGES;
        int gb_soc = (NNZ_SOC + SEDGES - 1) / SEDGES;
        scatter_lds<<<gb_ui, nthr, 0, stream>>>(ui_rows, ui_cols, ui_vals,
                                                cg_ui, U_N, pairs_ui, NNZ_UI, (U_N + 15) / 16, 16);
        scatter_lds<<<gb_ui, nthr, 0, stream>>>(ui_cols, ui_rows, ui_vals,
                                                cg_uiT, I_N, pairs_uiT, NNZ_UI, (I_N + 15) / 16, 16);
        scatter_lds<<<gb_soc, nthr, 0, stream>>>(soc_rows, soc_cols, soc_vals,
                                                 cg_soc, U_N, pairs_soc, NNZ_SOC, (U_N + 7) / 8, 8);
    }

    // 6) copy user_emb to output slots
    copy2_f4<<<(int)(UD / 4 + nthr - 1) / nthr, nthr, 0, stream>>>(
        (const float4*)user_emb, (float4*)o_ui0, (float4*)o_s0, (int)(UD / 4));

    const int xb_i = (I_N + 63) / 64;
    const int xb_u = (U_N + 63) / 64;

    // 7) T0
    {
        XfArgs xa;
        xa.src[0] = item_emb; xa.wbf[0] = wbfUI0; xa.dst[0] = Yi; xa.n[0] = I_N;
        xa.src[1] = user_emb; xa.wbf[1] = wbfUI0; xa.dst[1] = Yu; xa.n[1] = U_N;
        xa.src[2] = user_emb; xa.wbf[2] = wbfS0;  xa.dst[2] = Ys; xa.n[2] = U_N;
        xa.base[0] = 0; xa.base[1] = xb_i; xa.base[2] = xb_i + xb_u; xa.base[3] = xb_i + 2 * xb_u;
        xform_mfma<<<xa.base[3], nthr, 0, stream>>>(xa);
    }

    // 8) spmm L0
    {
        SpArgs pa;
        pa.rptr[0] = rp_ui;  pa.pairs[0] = pairs_ui;  pa.y[0] = Yi; pa.cur[0] = user_emb;
        pa.bias[0] = ui_b;  pa.gamma[0] = ln_ui_g;  pa.beta[0] = ln_ui_b;  pa.dst[0] = o_ui1;
        pa.n[0] = U_N; pa.nnzc[0] = NNZ_UI;
        pa.rptr[1] = rp_uiT; pa.pairs[1] = pairs_uiT; pa.y[1] = Yu; pa.cur[1] = item_emb;
        pa.bias[1] = ui_b;  pa.gamma[1] = ln_ui_g;  pa.beta[1] = ln_ui_b;  pa.dst[1] = o_ci;
        pa.n[1] = I_N; pa.nnzc[1] = NNZ_UI;
        pa.rptr[2] = rp_soc; pa.pairs[2] = pairs_soc; pa.y[2] = Ys; pa.cur[2] = user_emb;
        pa.bias[2] = soc_b; pa.gamma[2] = ln_soc_g; pa.beta[2] = ln_soc_b; pa.dst[2] = o_s1;
        pa.n[2] = U_N; pa.nnzc[2] = NNZ_SOC;
        pa.base[0] = 0; pa.base[1] = U_N / 16; pa.base[2] = U_N / 16 + I_N / 16;
        pa.base[3] = 2 * (U_N / 16) + I_N / 16;
        spmm_ln<<<pa.base[3], nthr, 0, stream>>>(pa);
    }

    // 9) T1
    {
        XfArgs xa;
        xa.src[0] = o_ci;  xa.wbf[0] = wbfUI1; xa.dst[0] = Yi; xa.n[0] = I_N;
        xa.src[1] = o_ui1; xa.wbf[1] = wbfUI1; xa.dst[1] = Yu; xa.n[1] = U_N;
        xa.src[2] = o_s1;  xa.wbf[2] = wbfS1;  xa.dst[2] = Ys; xa.n[2] = U_N;
        xa.base[0] = 0; xa.base[1] = xb_i; xa.base[2] = xb_i + xb_u; xa.base[3] = xb_i + 2 * xb_u;
        xform_mfma<<<xa.base[3], nthr, 0, stream>>>(xa);
    }

    // 10) spmm L1
    {
        SpArgs pa;
        pa.rptr[0] = rp_ui;  pa.pairs[0] = pairs_ui;  pa.y[0] = Yi; pa.cur[0] = o_ui1;
        pa.bias[0] = ui_b + 64;  pa.gamma[0] = ln_ui_g + 64;  pa.beta[0] = ln_ui_b + 64;
        pa.dst[0] = o_ui2;
        pa.n[0] = U_N; pa.nnzc[0] = NNZ_UI;
        pa.rptr[1] = rp_uiT; pa.pairs[1] = pairs_uiT; pa.y[1] = Yu; pa.cur[1] = o_ci;
        pa.bias[1] = ui_b + 64;  pa.gamma[1] = ln_ui_g + 64;  pa.beta[1] = ln_ui_b + 64;
        pa.dst[1] = o_ci;   // in-place: row read then written by same thread
        pa.n[1] = I_N; pa.nnzc[1] = NNZ_UI;
        pa.rptr[2] = rp_soc; pa.pairs[2] = pairs_soc; pa.y[2] = Ys; pa.cur[2] = o_s1;
        pa.bias[2] = soc_b + 64; pa.gamma[2] = ln_soc_g + 64; pa.beta[2] = ln_soc_b + 64;
        pa.dst[2] = o_s2;
        pa.n[2] = U_N; pa.nnzc[2] = NNZ_SOC;
        pa.base[0] = 0; pa.base[1] = U_N / 16; pa.base[2] = U_N / 16 + I_N / 16;
        pa.base[3] = 2 * (U_N / 16) + I_N / 16;
        spmm_ln<<<pa.base[3], nthr, 0, stream>>>(pa);
    }
}